// Round 6
// baseline (358.571 us; speedup 1.0000x reference)
//
#include <hip/hip_runtime.h>
#include <math.h>

#define N_NODES 50000
#define N_EDGES 800000
#define HD 256      // H*D
#define NHEAD 4
#define DH 64

typedef short bf16x8 __attribute__((ext_vector_type(8)));
typedef float f32x4 __attribute__((ext_vector_type(4)));

__device__ __forceinline__ unsigned short f2bf(float f) {  // RNE
    unsigned u = __float_as_uint(f);
    return (unsigned short)((u + 0x7fffu + ((u >> 16) & 1u)) >> 16);
}
__device__ __forceinline__ float bf2f(unsigned short h) {
    return __uint_as_float((unsigned)h << 16);
}

// ---------- pack W (fp32 [256][256] row-major) into per-lane MFMA B-frag layout ----------
// Wp[L][nt(16)][kt(8)][lane(64)][j(8)] = W[kt*32 + (lane>>4)*8 + j][nt*16 + (lane&15)]
__global__ void packw_k(const float* __restrict__ W0, const float* __restrict__ W1,
                        const float* __restrict__ W2, unsigned short* __restrict__ Wp) {
    int blk = blockIdx.x;           // 384 = 3 layers * 128 tiles
    int L = blk >> 7, t = blk & 127;
    const float* W = L == 0 ? W0 : L == 1 ? W1 : W2;
    int nt = t >> 3, kt = t & 7;
    int lane = threadIdx.x;
    int col = nt * 16 + (lane & 15);
    int kb = kt * 32 + (lane >> 4) * 8;
    unsigned short v[8];
#pragma unroll
    for (int j = 0; j < 8; j++) v[j] = f2bf(W[(size_t)(kb + j) * 256 + col]);
    *(bf16x8*)(Wp + ((size_t)(L * 128 + t) * 64 + lane) * 8) = *(bf16x8*)v;
}

// ---------- bf16 MFMA GEMM + fused el/er epilogue ----------
template <bool AFP32>
__global__ __launch_bounds__(256) void gemm_k(const void* __restrict__ Av,
                                              const unsigned short* __restrict__ Wp,
                                              const float* __restrict__ al,
                                              const float* __restrict__ ar,
                                              unsigned short* __restrict__ C,
                                              float* __restrict__ el,
                                              float* __restrict__ er, int M) {
    __shared__ unsigned short Asl[64 * 256];   // 32KB, XOR-swizzled bf16 A-tile
    int tid = threadIdx.x, wv = tid >> 6, lane = tid & 63;
    int bm = blockIdx.x * 64;
    if (AFP32) {
        const float* A = (const float*)Av;
#pragma unroll
        for (int i = 0; i < 8; i++) {
            int chunk = i * 256 + tid;
            int r = chunk >> 5, kc = (chunk & 31) * 8;
            float4 f0, f1;
            if (bm + r < M) {
                const float* p = A + (size_t)(bm + r) * 256 + kc;
                f0 = *(const float4*)p;
                f1 = *(const float4*)(p + 4);
            } else {
                f0 = f1 = make_float4(0.f, 0.f, 0.f, 0.f);
            }
            unsigned short tmp[8] = {f2bf(f0.x), f2bf(f0.y), f2bf(f0.z), f2bf(f0.w),
                                     f2bf(f1.x), f2bf(f1.y), f2bf(f1.z), f2bf(f1.w)};
            int b = (r * 512 + kc * 2) ^ ((r & 7) << 4);
            *(bf16x8*)((char*)Asl + b) = *(bf16x8*)tmp;
        }
    } else {
        const unsigned short* A = (const unsigned short*)Av;
#pragma unroll
        for (int i = 0; i < 8; i++) {
            int chunk = i * 256 + tid;
            int r = chunk >> 5, c16 = chunk & 31;
            int grow = bm + r; if (grow >= M) grow = M - 1;   // clamp; OOB rows unused
            bf16x8 v = *(const bf16x8*)(A + (size_t)grow * 256 + c16 * 8);
            int b = (r * 512 + c16 * 16) ^ ((r & 7) << 4);
            *(bf16x8*)((char*)Asl + b) = v;
        }
    }
    __syncthreads();
    f32x4 acc[4][4] = {};
    const unsigned short* wbase = Wp + (size_t)(wv * 4) * 8 * 64 * 8;  // nt base = wv*4
#pragma unroll
    for (int kk = 0; kk < 8; kk++) {
        bf16x8 a[4], b[4];
#pragma unroll
        for (int m = 0; m < 4; m++) {
            int r = m * 16 + (lane & 15);
            int kb = kk * 32 + (lane >> 4) * 8;
            int byt = (r * 512 + kb * 2) ^ ((r & 7) << 4);
            a[m] = *(const bf16x8*)((const char*)Asl + byt);
        }
#pragma unroll
        for (int n = 0; n < 4; n++)
            b[n] = *(const bf16x8*)(wbase + ((size_t)(n * 8 + kk) * 64 + lane) * 8);
#pragma unroll
        for (int m = 0; m < 4; m++)
#pragma unroll
            for (int n = 0; n < 4; n++)
                acc[m][n] = __builtin_amdgcn_mfma_f32_16x16x32_bf16(a[m], b[n],
                                                                    acc[m][n], 0, 0, 0);
    }
    int rr = lane >> 4, cc = lane & 15;
    float alv[4], arv[4];
#pragma unroll
    for (int n = 0; n < 4; n++) {
        alv[n] = al[wv * 64 + n * 16 + cc];
        arv[n] = ar[wv * 64 + n * 16 + cc];
    }
#pragma unroll
    for (int m = 0; m < 4; m++) {
#pragma unroll
        for (int r = 0; r < 4; r++) {
            int row = bm + m * 16 + rr * 4 + r;
            float ep = 0.f, rp = 0.f;
#pragma unroll
            for (int n = 0; n < 4; n++) {
                ep = fmaf(acc[m][n][r], alv[n], ep);
                rp = fmaf(acc[m][n][r], arv[n], rp);
            }
#pragma unroll
            for (int o = 1; o < 16; o <<= 1) {
                ep += __shfl_xor(ep, o);
                rp += __shfl_xor(rp, o);
            }
            if (row < M) {
                if (cc == 0) {
                    el[(size_t)row * NHEAD + wv] = ep;
                    er[(size_t)row * NHEAD + wv] = rp;
                }
#pragma unroll
                for (int n = 0; n < 4; n++)
                    C[(size_t)row * 256 + wv * 64 + n * 16 + cc] = f2bf(acc[m][n][r]);
            }
        }
    }
}

// ---------- CSR build ----------
__global__ void hist_k(const int* __restrict__ dst, int* __restrict__ deg) {
    int e = blockIdx.x * 256 + threadIdx.x;
    if (e < N_EDGES) atomicAdd(&deg[dst[e]], 1);
}

__global__ __launch_bounds__(1024) void scan1_k(const int* __restrict__ deg,
                                                int* __restrict__ rowptr,
                                                int* __restrict__ bsum) {
    __shared__ int wsum[16];
    int tid = threadIdx.x, lane = tid & 63, wv = tid >> 6;
    int i = blockIdx.x * 1024 + tid;
    int v = (i < N_NODES) ? deg[i] : 0;
    int sc = v;
#pragma unroll
    for (int o = 1; o < 64; o <<= 1) {
        int t = __shfl_up(sc, o);
        if (lane >= o) sc += t;
    }
    if (lane == 63) wsum[wv] = sc;
    __syncthreads();
    if (wv == 0 && lane < 16) {
        int ws = wsum[lane];
#pragma unroll
        for (int o = 1; o < 16; o <<= 1) {
            int t = __shfl_up(ws, o);
            if (lane >= o) ws += t;
        }
        wsum[lane] = ws;
    }
    __syncthreads();
    int incl = sc + (wv > 0 ? wsum[wv - 1] : 0);
    if (i < N_NODES) rowptr[i + 1] = incl;
    if (tid == 1023) bsum[blockIdx.x] = incl;
}

// scan block-sums locally (nb<=64), add offsets, emit rowptr + cursor
__global__ __launch_bounds__(1024) void scan3_k(int* __restrict__ rowptr,
                                                const int* __restrict__ bsum,
                                                int* __restrict__ cursor, int nb) {
    __shared__ int boff_s;
    int tid = threadIdx.x;
    if (tid < 64) {
        int v = (tid < nb) ? bsum[tid] : 0;
        int sc = v;
#pragma unroll
        for (int o = 1; o < 64; o <<= 1) {
            int t = __shfl_up(sc, o);
            if ((tid & 63) >= o) sc += t;
        }
        if (tid == (int)blockIdx.x) boff_s = sc - v;  // exclusive prefix
    }
    __syncthreads();
    int off = boff_s;
    int i = blockIdx.x * 1024 + tid;
    if (blockIdx.x == 0 && tid == 0) { rowptr[0] = 0; cursor[0] = 0; }
    if (i < N_NODES) {
        int v = rowptr[i + 1] + off;
        rowptr[i + 1] = v;
        if (i + 1 < N_NODES) cursor[i + 1] = v;
    }
}

__global__ void scatter_k(const int* __restrict__ src, const int* __restrict__ dst,
                          int* __restrict__ cursor, int* __restrict__ csr_src) {
    int e = blockIdx.x * 256 + threadIdx.x;
    if (e >= N_EDGES) return;
    int pos = atomicAdd(&cursor[dst[e]], 1);
    csr_src[pos] = src[e];
}

// ---------- fused per-dst softmax (max-free) + gather-aggregate + epilogue ----------
// MODE 0: no resid, ELU, out bf16; MODE 1: bf16 resid, ELU, out bf16;
// MODE 2: bf16 resid, no act, head-mean, out fp32
// Lane layout: lane holds dims [4*lane, 4*lane+4); head = lane>>4.
template <int MODE>
__global__ __launch_bounds__(256) void agg_k(const int* __restrict__ rowptr,
                                             const int* __restrict__ csr_src,
                                             const float* __restrict__ el,
                                             const float* __restrict__ er,
                                             const unsigned short* __restrict__ feat,
                                             const unsigned short* __restrict__ resid,
                                             const float* __restrict__ bias,
                                             float* __restrict__ out,
                                             unsigned short* __restrict__ hb) {
    __shared__ int   ws_s[4][64];       // byte offsets s*512
    __shared__ float ws_w[4][4][68];    // [wave][head][edge], pad 68 de-banks
    int wv = threadIdx.x >> 6, lane = threadIdx.x & 63;
    int node = blockIdx.x * 4 + wv;
    if (node >= N_NODES) return;
    int beg = rowptr[node], end = rowptr[node + 1];
    float4 er4 = *(const float4*)(er + (size_t)node * 4);
    float4 acc0 = make_float4(0.f, 0.f, 0.f, 0.f);
    float4 acc1 = make_float4(0.f, 0.f, 0.f, 0.f);
    float4 den = make_float4(0.f, 0.f, 0.f, 0.f);
    int h = lane >> 4;
    int l8 = lane * 8;
    const char* fb = (const char*)feat;
    for (int base = beg; base < end; base += 64) {
        int j = base + lane;
        int soff = 0;
        float4 w = make_float4(0.f, 0.f, 0.f, 0.f);
        if (j < end) {
            int s = csr_src[j];
            soff = s << 9;              // byte offset of feat row (256 bf16)
            float4 l4 = *(const float4*)(el + (size_t)s * 4);
            float vx = l4.x + er4.x; vx = vx > 0.f ? vx : 0.2f * vx;
            float vy = l4.y + er4.y; vy = vy > 0.f ? vy : 0.2f * vy;
            float vz = l4.z + er4.z; vz = vz > 0.f ? vz : 0.2f * vz;
            float vw = l4.w + er4.w; vw = vw > 0.f ? vw : 0.2f * vw;
            // max-free softmax: |v| = O(3), exp cannot overflow fp32
            w.x = expf(vx); w.y = expf(vy); w.z = expf(vz); w.w = expf(vw);
            den.x += w.x; den.y += w.y; den.z += w.z; den.w += w.w;
        }
        ws_s[wv][lane] = soff;          // dummy lanes: soff=0, w=0
        ws_w[wv][0][lane] = w.x;
        ws_w[wv][1][lane] = w.y;
        ws_w[wv][2][lane] = w.z;
        ws_w[wv][3][lane] = w.w;
        __builtin_amdgcn_wave_barrier();
        int cnt = end - base; if (cnt > 64) cnt = 64;
        int cnt4 = (cnt + 3) & ~3;      // zero-padded: no tail loop
        for (int k = 0; k < cnt4; k += 4) {
            int4   so = *(const int4*)&ws_s[wv][k];     // broadcast
            float4 w4 = *(const float4*)&ws_w[wv][h][k]; // b128, 4 bank-quads
            ushort4 u0 = *(const ushort4*)(fb + (so.x + l8));
            ushort4 u1 = *(const ushort4*)(fb + (so.y + l8));
            ushort4 u2 = *(const ushort4*)(fb + (so.z + l8));
            ushort4 u3 = *(const ushort4*)(fb + (so.w + l8));
            acc0.x = fmaf(w4.x, bf2f(u0.x), acc0.x);
            acc0.y = fmaf(w4.x, bf2f(u0.y), acc0.y);
            acc0.z = fmaf(w4.x, bf2f(u0.z), acc0.z);
            acc0.w = fmaf(w4.x, bf2f(u0.w), acc0.w);
            acc1.x = fmaf(w4.y, bf2f(u1.x), acc1.x);
            acc1.y = fmaf(w4.y, bf2f(u1.y), acc1.y);
            acc1.z = fmaf(w4.y, bf2f(u1.z), acc1.z);
            acc1.w = fmaf(w4.y, bf2f(u1.w), acc1.w);
            acc0.x = fmaf(w4.z, bf2f(u2.x), acc0.x);
            acc0.y = fmaf(w4.z, bf2f(u2.y), acc0.y);
            acc0.z = fmaf(w4.z, bf2f(u2.z), acc0.z);
            acc0.w = fmaf(w4.z, bf2f(u2.w), acc0.w);
            acc1.x = fmaf(w4.w, bf2f(u3.x), acc1.x);
            acc1.y = fmaf(w4.w, bf2f(u3.y), acc1.y);
            acc1.z = fmaf(w4.w, bf2f(u3.z), acc1.z);
            acc1.w = fmaf(w4.w, bf2f(u3.w), acc1.w);
        }
        __builtin_amdgcn_wave_barrier();
    }
    float4 acc;
    acc.x = acc0.x + acc1.x; acc.y = acc0.y + acc1.y;
    acc.z = acc0.z + acc1.z; acc.w = acc0.w + acc1.w;
#pragma unroll
    for (int o = 1; o < 64; o <<= 1) {
        den.x += __shfl_xor(den.x, o);
        den.y += __shfl_xor(den.y, o);
        den.z += __shfl_xor(den.z, o);
        den.w += __shfl_xor(den.w, o);
    }
    float den_me = h == 0 ? den.x : h == 1 ? den.y : h == 2 ? den.z : den.w;
    float r = den_me > 0.f ? 1.f / den_me : 0.f;
    int col = lane * 4;
    float4 b4 = *(const float4*)(bias + col);
    float4 o4;
    o4.x = acc.x * r + b4.x;
    o4.y = acc.y * r + b4.y;
    o4.z = acc.z * r + b4.z;
    o4.w = acc.w * r + b4.w;
    if (MODE >= 1) {
        ushort4 r4 = *(const ushort4*)(resid + (size_t)node * HD + col);
        o4.x += bf2f(r4.x); o4.y += bf2f(r4.y);
        o4.z += bf2f(r4.z); o4.w += bf2f(r4.w);
    }
    if (MODE <= 1) {
        o4.x = o4.x > 0.f ? o4.x : expm1f(o4.x);
        o4.y = o4.y > 0.f ? o4.y : expm1f(o4.y);
        o4.z = o4.z > 0.f ? o4.z : expm1f(o4.z);
        o4.w = o4.w > 0.f ? o4.w : expm1f(o4.w);
        ushort4 hv;
        hv.x = f2bf(o4.x); hv.y = f2bf(o4.y); hv.z = f2bf(o4.z); hv.w = f2bf(o4.w);
        *(ushort4*)(hb + (size_t)node * HD + col) = hv;
    } else {
        o4.x += __shfl_xor(o4.x, 16); o4.x += __shfl_xor(o4.x, 32);
        o4.y += __shfl_xor(o4.y, 16); o4.y += __shfl_xor(o4.y, 32);
        o4.z += __shfl_xor(o4.z, 16); o4.z += __shfl_xor(o4.z, 32);
        o4.w += __shfl_xor(o4.w, 16); o4.w += __shfl_xor(o4.w, 32);
        if (lane < 16) {
            float4 ov = make_float4(o4.x * 0.25f, o4.y * 0.25f,
                                    o4.z * 0.25f, o4.w * 0.25f);
            *(float4*)(out + (size_t)node * DH + lane * 4) = ov;
        }
    }
}

extern "C" void kernel_launch(void* const* d_in, const int* in_sizes, int n_in,
                              void* d_out, int out_size, void* d_ws, size_t ws_size,
                              hipStream_t stream) {
    const float* x   = (const float*)d_in[0];
    const int*   src = (const int*)d_in[1];
    const int*   dst = (const int*)d_in[2];
    const float* W[3]  = {(const float*)d_in[3], (const float*)d_in[7],  (const float*)d_in[11]};
    const float* al[3] = {(const float*)d_in[4], (const float*)d_in[8],  (const float*)d_in[12]};
    const float* ar[3] = {(const float*)d_in[5], (const float*)d_in[9],  (const float*)d_in[13]};
    const float* bb[3] = {(const float*)d_in[6], (const float*)d_in[10], (const float*)d_in[14]};

    size_t big = (size_t)N_NODES * HD;      // 12.8M elems
    unsigned short* featb = (unsigned short*)d_ws;
    unsigned short* hb1 = featb + big;
    unsigned short* hb2 = hb1 + big;
    float* el = (float*)(hb2 + big);
    float* er = el + (size_t)N_NODES * NHEAD;
    int* deg     = (int*)(er + (size_t)N_NODES * NHEAD);
    int* rowptr  = deg + 50048;
    int* cursor  = rowptr + 50048;
    int* csr_src = cursor + 50048;          // E ints
    int* bsum    = csr_src + N_EDGES;       // 64 ints
    unsigned short* Wp = (unsigned short*)(bsum + 64);  // 3*128*64*8

    const int NB = (N_NODES + 1023) / 1024;  // 49

    // ---- weight pack + CSR build (once per launch) ----
    packw_k<<<384, 64, 0, stream>>>(W[0], W[1], W[2], Wp);
    hipMemsetAsync(deg, 0, (size_t)N_NODES * 4, stream);
    hist_k<<<N_EDGES / 256, 256, 0, stream>>>(dst, deg);
    scan1_k<<<NB, 1024, 0, stream>>>(deg, rowptr, bsum);
    scan3_k<<<NB, 1024, 0, stream>>>(rowptr, bsum, cursor, NB);
    scatter_k<<<N_EDGES / 256, 256, 0, stream>>>(src, dst, cursor, csr_src);

    int ggrid = (N_NODES + 63) / 64;
    int agrid = (N_NODES + 3) / 4;

    gemm_k<true><<<ggrid, 256, 0, stream>>>(x, Wp, al[0], ar[0], featb, el, er, N_NODES);
    agg_k<0><<<agrid, 256, 0, stream>>>(rowptr, csr_src, el, er, featb,
                                        nullptr, bb[0], nullptr, hb1);
    gemm_k<false><<<ggrid, 256, 0, stream>>>(hb1, Wp + (size_t)1 * 128 * 64 * 8,
                                             al[1], ar[1], featb, el, er, N_NODES);
    agg_k<1><<<agrid, 256, 0, stream>>>(rowptr, csr_src, el, er, featb,
                                        hb1, bb[1], nullptr, hb2);
    gemm_k<false><<<ggrid, 256, 0, stream>>>(hb2, Wp + (size_t)2 * 128 * 64 * 8,
                                             al[2], ar[2], featb, el, er, N_NODES);
    agg_k<2><<<agrid, 256, 0, stream>>>(rowptr, csr_src, el, er, featb,
                                        hb2, bb[2], (float*)d_out, nullptr);
}

// Round 7
// 350.903 us; speedup vs baseline: 1.0219x; 1.0219x over previous
//
#include <hip/hip_runtime.h>
#include <math.h>

#define N_NODES 50000
#define N_EDGES 800000
#define HD 256      // H*D
#define NHEAD 4
#define DH 64

typedef short bf16x8 __attribute__((ext_vector_type(8)));
typedef float f32x4 __attribute__((ext_vector_type(4)));

__device__ __forceinline__ unsigned short f2bf(float f) {  // RNE
    unsigned u = __float_as_uint(f);
    return (unsigned short)((u + 0x7fffu + ((u >> 16) & 1u)) >> 16);
}
__device__ __forceinline__ float bf2f(unsigned short h) {
    return __uint_as_float((unsigned)h << 16);
}
// π: stored col c' holds original col orig(c') = (c'&~63) | ((c'&3)*16 + ((c'>>2)&15))
__device__ __forceinline__ int origk(int k) {
    return (k & ~63) | ((k & 3) * 16 + ((k >> 2) & 15));
}

// ---------- pack W into per-lane MFMA B-frag layout ----------
// Wp[L][nt(16)][kt(8)][lane(64)][j(8)] = W[krow][nt*16 + (lane&15)]
// krow = kt*32+(lane>>4)*8+j for L==0 (A natural); origk(...) for L>0 (A in π)
__global__ void packw_k(const float* __restrict__ W0, const float* __restrict__ W1,
                        const float* __restrict__ W2, unsigned short* __restrict__ Wp) {
    int blk = blockIdx.x;           // 384 = 3 layers * 128 tiles
    int L = blk >> 7, t = blk & 127;
    const float* W = L == 0 ? W0 : L == 1 ? W1 : W2;
    int nt = t >> 3, kt = t & 7;
    int lane = threadIdx.x;
    int col = nt * 16 + (lane & 15);
    int kb = kt * 32 + (lane >> 4) * 8;
    unsigned short v[8];
#pragma unroll
    for (int j = 0; j < 8; j++) {
        int k = kb + j;
        if (L > 0) k = origk(k);
        v[j] = f2bf(W[(size_t)k * 256 + col]);
    }
    *(bf16x8*)(Wp + ((size_t)(L * 128 + t) * 64 + lane) * 8) = *(bf16x8*)v;
}

// ---------- bf16 MFMA GEMM + fused el/er epilogue; C stored in π layout ----------
template <bool AFP32>
__global__ __launch_bounds__(256) void gemm_k(const void* __restrict__ Av,
                                              const unsigned short* __restrict__ Wp,
                                              const float* __restrict__ al,
                                              const float* __restrict__ ar,
                                              unsigned short* __restrict__ C,
                                              float* __restrict__ el,
                                              float* __restrict__ er, int M) {
    __shared__ unsigned short Asl[64 * 256];   // 32KB, XOR-swizzled bf16 A-tile
    int tid = threadIdx.x, wv = tid >> 6, lane = tid & 63;
    int bm = blockIdx.x * 64;
    if (AFP32) {
        const float* A = (const float*)Av;
#pragma unroll
        for (int i = 0; i < 8; i++) {
            int chunk = i * 256 + tid;
            int r = chunk >> 5, kc = (chunk & 31) * 8;
            float4 f0, f1;
            if (bm + r < M) {
                const float* p = A + (size_t)(bm + r) * 256 + kc;
                f0 = *(const float4*)p;
                f1 = *(const float4*)(p + 4);
            } else {
                f0 = f1 = make_float4(0.f, 0.f, 0.f, 0.f);
            }
            unsigned short tmp[8] = {f2bf(f0.x), f2bf(f0.y), f2bf(f0.z), f2bf(f0.w),
                                     f2bf(f1.x), f2bf(f1.y), f2bf(f1.z), f2bf(f1.w)};
            int b = (r * 512 + kc * 2) ^ ((r & 7) << 4);
            *(bf16x8*)((char*)Asl + b) = *(bf16x8*)tmp;
        }
    } else {
        // global_load_lds: linear LDS dest, inverse-swizzled per-lane global source.
        // slot chunk holds D[r][(chunk&31)^(r&7)]; MFMA reads slot (r*32+c16)^(r&7).
        const unsigned short* A = (const unsigned short*)Av;
#pragma unroll
        for (int i = 0; i < 8; i++) {
            int chunk = i * 256 + wv * 64 + lane;
            int r = chunk >> 5;
            int c16 = (chunk & 31) ^ (r & 7);
            const unsigned short* src = A + (size_t)(bm + r) * 256 + c16 * 8;
            __builtin_amdgcn_global_load_lds(
                (const __attribute__((address_space(1))) unsigned int*)src,
                (__attribute__((address_space(3))) unsigned int*)
                    ((char*)Asl + (size_t)(i * 256 + wv * 64) * 16),
                16, 0, 0);
        }
    }
    __syncthreads();
    f32x4 acc[4][4] = {};
    const unsigned short* wbase = Wp + (size_t)(wv * 4) * 8 * 64 * 8;  // nt base = wv*4
#pragma unroll
    for (int kk = 0; kk < 8; kk++) {
        bf16x8 a[4], b[4];
#pragma unroll
        for (int m = 0; m < 4; m++) {
            int r = m * 16 + (lane & 15);
            int kb = kk * 32 + (lane >> 4) * 8;
            int byt = (r * 512 + kb * 2) ^ ((r & 7) << 4);
            a[m] = *(const bf16x8*)((const char*)Asl + byt);
        }
#pragma unroll
        for (int n = 0; n < 4; n++)
            b[n] = *(const bf16x8*)(wbase + ((size_t)(n * 8 + kk) * 64 + lane) * 8);
#pragma unroll
        for (int m = 0; m < 4; m++)
#pragma unroll
            for (int n = 0; n < 4; n++)
                acc[m][n] = __builtin_amdgcn_mfma_f32_16x16x32_bf16(a[m], b[n],
                                                                    acc[m][n], 0, 0, 0);
    }
    int rr = lane >> 4, cc = lane & 15;
    // ---- el/er: butterfly transpose-reduce (16 rows per wave-quarter group) ----
    float alv[4], arv[4];
#pragma unroll
    for (int n = 0; n < 4; n++) {
        alv[n] = al[wv * 64 + n * 16 + cc];
        arv[n] = ar[wv * 64 + n * 16 + cc];
    }
    float vl[16], vr[16];
#pragma unroll
    for (int m = 0; m < 4; m++)
#pragma unroll
        for (int r = 0; r < 4; r++) {
            float ep = 0.f, rp = 0.f;
#pragma unroll
            for (int n = 0; n < 4; n++) {
                ep = fmaf(acc[m][n][r], alv[n], ep);
                rp = fmaf(acc[m][n][r], arv[n], rp);
            }
            vl[m * 4 + r] = ep;
            vr[m * 4 + r] = rp;
        }
    // step s: keep v[2i+b], send v[2i+(1-b)] (b = bit of cc); recv = partner's kept pair
    float l8[8], r8[8];
#pragma unroll
    for (int i = 0; i < 8; i++) {
        float xs = (cc & 1) ? vl[2 * i] : vl[2 * i + 1];
        float xk = (cc & 1) ? vl[2 * i + 1] : vl[2 * i];
        l8[i] = xk + __shfl_xor(xs, 1);
        float ys = (cc & 1) ? vr[2 * i] : vr[2 * i + 1];
        float yk = (cc & 1) ? vr[2 * i + 1] : vr[2 * i];
        r8[i] = yk + __shfl_xor(ys, 1);
    }
    float l4[4], r4[4];
#pragma unroll
    for (int i = 0; i < 4; i++) {
        float xs = (cc & 2) ? l8[2 * i] : l8[2 * i + 1];
        float xk = (cc & 2) ? l8[2 * i + 1] : l8[2 * i];
        l4[i] = xk + __shfl_xor(xs, 2);
        float ys = (cc & 2) ? r8[2 * i] : r8[2 * i + 1];
        float yk = (cc & 2) ? r8[2 * i + 1] : r8[2 * i];
        r4[i] = yk + __shfl_xor(ys, 2);
    }
    float l2[2], r2[2];
#pragma unroll
    for (int i = 0; i < 2; i++) {
        float xs = (cc & 4) ? l4[2 * i] : l4[2 * i + 1];
        float xk = (cc & 4) ? l4[2 * i + 1] : l4[2 * i];
        l2[i] = xk + __shfl_xor(xs, 4);
        float ys = (cc & 4) ? r4[2 * i] : r4[2 * i + 1];
        float yk = (cc & 4) ? r4[2 * i + 1] : r4[2 * i];
        r2[i] = yk + __shfl_xor(ys, 4);
    }
    {
        float xs = (cc & 8) ? l2[0] : l2[1];
        float xk = (cc & 8) ? l2[1] : l2[0];
        float lv = xk + __shfl_xor(xs, 8);
        float ys = (cc & 8) ? r2[0] : r2[1];
        float yk = (cc & 8) ? r2[1] : r2[0];
        float rv = yk + __shfl_xor(ys, 8);
        // lane rr*16+cc holds row bm + (cc>>2)*16 + rr*4 + (cc&3), head wv
        int row_e = bm + (cc >> 2) * 16 + rr * 4 + (cc & 3);
        if (row_e < M) {
            el[(size_t)row_e * NHEAD + wv] = lv;
            er[(size_t)row_e * NHEAD + wv] = rv;
        }
    }
    // ---- C store in π layout: lane's 4 cols contiguous (8B coalesced) ----
#pragma unroll
    for (int m = 0; m < 4; m++) {
#pragma unroll
        for (int r = 0; r < 4; r++) {
            int row = bm + m * 16 + rr * 4 + r;
            if (row < M) {
                unsigned short p4[4] = {f2bf(acc[m][0][r]), f2bf(acc[m][1][r]),
                                        f2bf(acc[m][2][r]), f2bf(acc[m][3][r])};
                *(ushort4*)(C + (size_t)row * 256 + wv * 64 + cc * 4) = *(ushort4*)p4;
            }
        }
    }
}

// ---------- CSR build ----------
__global__ void hist_k(const int* __restrict__ dst, int* __restrict__ deg) {
    int e = blockIdx.x * 256 + threadIdx.x;
    if (e < N_EDGES) atomicAdd(&deg[dst[e]], 1);
}

__global__ __launch_bounds__(1024) void scan1_k(const int* __restrict__ deg,
                                                int* __restrict__ rowptr,
                                                int* __restrict__ bsum) {
    __shared__ int wsum[16];
    int tid = threadIdx.x, lane = tid & 63, wv = tid >> 6;
    int i = blockIdx.x * 1024 + tid;
    int v = (i < N_NODES) ? deg[i] : 0;
    int sc = v;
#pragma unroll
    for (int o = 1; o < 64; o <<= 1) {
        int t = __shfl_up(sc, o);
        if (lane >= o) sc += t;
    }
    if (lane == 63) wsum[wv] = sc;
    __syncthreads();
    if (wv == 0 && lane < 16) {
        int ws = wsum[lane];
#pragma unroll
        for (int o = 1; o < 16; o <<= 1) {
            int t = __shfl_up(ws, o);
            if (lane >= o) ws += t;
        }
        wsum[lane] = ws;
    }
    __syncthreads();
    int incl = sc + (wv > 0 ? wsum[wv - 1] : 0);
    if (i < N_NODES) rowptr[i + 1] = incl;
    if (tid == 1023) bsum[blockIdx.x] = incl;
}

__global__ __launch_bounds__(1024) void scan3_k(int* __restrict__ rowptr,
                                                const int* __restrict__ bsum,
                                                int* __restrict__ cursor, int nb) {
    __shared__ int boff_s;
    int tid = threadIdx.x;
    if (tid < 64) {
        int v = (tid < nb) ? bsum[tid] : 0;
        int sc = v;
#pragma unroll
        for (int o = 1; o < 64; o <<= 1) {
            int t = __shfl_up(sc, o);
            if ((tid & 63) >= o) sc += t;
        }
        if (tid == (int)blockIdx.x) boff_s = sc - v;  // exclusive prefix
    }
    __syncthreads();
    int off = boff_s;
    int i = blockIdx.x * 1024 + tid;
    if (blockIdx.x == 0 && tid == 0) { rowptr[0] = 0; cursor[0] = 0; }
    if (i < N_NODES) {
        int v = rowptr[i + 1] + off;
        rowptr[i + 1] = v;
        if (i + 1 < N_NODES) cursor[i + 1] = v;
    }
}

__global__ void scatter_k(const int* __restrict__ src, const int* __restrict__ dst,
                          int* __restrict__ cursor, int* __restrict__ csr_src) {
    int e = blockIdx.x * 256 + threadIdx.x;
    if (e >= N_EDGES) return;
    int pos = atomicAdd(&cursor[dst[e]], 1);
    csr_src[pos] = src[e];
}

// ---------- fused per-dst softmax (max-free) + gather-aggregate + epilogue ----------
// feat/resid/hb are in π layout (opaque per-head dims). bias loaded inverse-permuted.
// MODE 0: no resid, ELU, out bf16; MODE 1: bf16 resid, ELU, out bf16;
// MODE 2: bf16 resid, no act, head-mean, fp32 out (unpermuted)
template <int MODE>
__global__ __launch_bounds__(256) void agg_k(const int* __restrict__ rowptr,
                                             const int* __restrict__ csr_src,
                                             const float* __restrict__ el,
                                             const float* __restrict__ er,
                                             const unsigned short* __restrict__ feat,
                                             const unsigned short* __restrict__ resid,
                                             const float* __restrict__ bias,
                                             float* __restrict__ out,
                                             unsigned short* __restrict__ hb) {
    __shared__ int   ws_s[4][64];       // byte offsets s*512
    __shared__ float ws_w[4][4][68];    // [wave][head][edge], pad 68 de-banks
    int wv = threadIdx.x >> 6, lane = threadIdx.x & 63;
    int node = blockIdx.x * 4 + wv;
    if (node >= N_NODES) return;
    int beg = rowptr[node], end = rowptr[node + 1];
    float4 er4 = *(const float4*)(er + (size_t)node * 4);
    float4 acc0 = make_float4(0.f, 0.f, 0.f, 0.f);
    float4 acc1 = make_float4(0.f, 0.f, 0.f, 0.f);
    float4 den = make_float4(0.f, 0.f, 0.f, 0.f);
    int h = lane >> 4;
    int l8 = lane * 8;
    const char* fb = (const char*)feat;
    for (int base = beg; base < end; base += 64) {
        int j = base + lane;
        int soff = 0;
        float4 w = make_float4(0.f, 0.f, 0.f, 0.f);
        if (j < end) {
            int s = csr_src[j];
            soff = s << 9;              // byte offset of feat row (256 bf16)
            float4 l4 = *(const float4*)(el + (size_t)s * 4);
            float vx = l4.x + er4.x; vx = vx > 0.f ? vx : 0.2f * vx;
            float vy = l4.y + er4.y; vy = vy > 0.f ? vy : 0.2f * vy;
            float vz = l4.z + er4.z; vz = vz > 0.f ? vz : 0.2f * vz;
            float vw = l4.w + er4.w; vw = vw > 0.f ? vw : 0.2f * vw;
            // max-free softmax: |v| = O(3), exp cannot overflow fp32
            w.x = expf(vx); w.y = expf(vy); w.z = expf(vz); w.w = expf(vw);
            den.x += w.x; den.y += w.y; den.z += w.z; den.w += w.w;
        }
        ws_s[wv][lane] = soff;          // dummy lanes: soff=0, w=0
        ws_w[wv][0][lane] = w.x;
        ws_w[wv][1][lane] = w.y;
        ws_w[wv][2][lane] = w.z;
        ws_w[wv][3][lane] = w.w;
        __builtin_amdgcn_wave_barrier();
        int cnt = end - base; if (cnt > 64) cnt = 64;
        int cnt4 = (cnt + 3) & ~3;      // zero-padded: no tail loop
        for (int k = 0; k < cnt4; k += 4) {
            int4   so = *(const int4*)&ws_s[wv][k];      // broadcast
            float4 w4 = *(const float4*)&ws_w[wv][h][k];
            ushort4 u0 = *(const ushort4*)(fb + (so.x + l8));
            ushort4 u1 = *(const ushort4*)(fb + (so.y + l8));
            ushort4 u2 = *(const ushort4*)(fb + (so.z + l8));
            ushort4 u3 = *(const ushort4*)(fb + (so.w + l8));
            acc0.x = fmaf(w4.x, bf2f(u0.x), acc0.x);
            acc0.y = fmaf(w4.x, bf2f(u0.y), acc0.y);
            acc0.z = fmaf(w4.x, bf2f(u0.z), acc0.z);
            acc0.w = fmaf(w4.x, bf2f(u0.w), acc0.w);
            acc1.x = fmaf(w4.y, bf2f(u1.x), acc1.x);
            acc1.y = fmaf(w4.y, bf2f(u1.y), acc1.y);
            acc1.z = fmaf(w4.y, bf2f(u1.z), acc1.z);
            acc1.w = fmaf(w4.y, bf2f(u1.w), acc1.w);
            acc0.x = fmaf(w4.z, bf2f(u2.x), acc0.x);
            acc0.y = fmaf(w4.z, bf2f(u2.y), acc0.y);
            acc0.z = fmaf(w4.z, bf2f(u2.z), acc0.z);
            acc0.w = fmaf(w4.z, bf2f(u2.w), acc0.w);
            acc1.x = fmaf(w4.w, bf2f(u3.x), acc1.x);
            acc1.y = fmaf(w4.w, bf2f(u3.y), acc1.y);
            acc1.z = fmaf(w4.w, bf2f(u3.z), acc1.z);
            acc1.w = fmaf(w4.w, bf2f(u3.w), acc1.w);
        }
        __builtin_amdgcn_wave_barrier();
    }
    float4 acc;
    acc.x = acc0.x + acc1.x; acc.y = acc0.y + acc1.y;
    acc.z = acc0.z + acc1.z; acc.w = acc0.w + acc1.w;
#pragma unroll
    for (int o = 1; o < 64; o <<= 1) {
        den.x += __shfl_xor(den.x, o);
        den.y += __shfl_xor(den.y, o);
        den.z += __shfl_xor(den.z, o);
        den.w += __shfl_xor(den.w, o);
    }
    float den_me = h == 0 ? den.x : h == 1 ? den.y : h == 2 ? den.z : den.w;
    float r = den_me > 0.f ? 1.f / den_me : 0.f;
    int cc = lane & 15;
    // bias in original order: stored dim c'=cc*4+i  ->  orig col i*16+cc (within head)
    float4 b4;
    b4.x = bias[h * 64 + 0 * 16 + cc];
    b4.y = bias[h * 64 + 1 * 16 + cc];
    b4.z = bias[h * 64 + 2 * 16 + cc];
    b4.w = bias[h * 64 + 3 * 16 + cc];
    float4 o4;
    o4.x = acc.x * r + b4.x;
    o4.y = acc.y * r + b4.y;
    o4.z = acc.z * r + b4.z;
    o4.w = acc.w * r + b4.w;
    if (MODE >= 1) {
        ushort4 r4 = *(const ushort4*)(resid + (size_t)node * HD + lane * 4);
        o4.x += bf2f(r4.x); o4.y += bf2f(r4.y);
        o4.z += bf2f(r4.z); o4.w += bf2f(r4.w);
    }
    if (MODE <= 1) {
        o4.x = o4.x > 0.f ? o4.x : expm1f(o4.x);
        o4.y = o4.y > 0.f ? o4.y : expm1f(o4.y);
        o4.z = o4.z > 0.f ? o4.z : expm1f(o4.z);
        o4.w = o4.w > 0.f ? o4.w : expm1f(o4.w);
        ushort4 hv;
        hv.x = f2bf(o4.x); hv.y = f2bf(o4.y); hv.z = f2bf(o4.z); hv.w = f2bf(o4.w);
        *(ushort4*)(hb + (size_t)node * HD + lane * 4) = hv;
    } else {
        o4.x += __shfl_xor(o4.x, 16); o4.x += __shfl_xor(o4.x, 32);
        o4.y += __shfl_xor(o4.y, 16); o4.y += __shfl_xor(o4.y, 32);
        o4.z += __shfl_xor(o4.z, 16); o4.z += __shfl_xor(o4.z, 32);
        o4.w += __shfl_xor(o4.w, 16); o4.w += __shfl_xor(o4.w, 32);
        if (lane < 16) {
            // stored c' = lane*4+i  ->  true dim i*16+lane
            float* po = out + (size_t)node * DH;
            po[0 * 16 + lane] = o4.x * 0.25f;
            po[1 * 16 + lane] = o4.y * 0.25f;
            po[2 * 16 + lane] = o4.z * 0.25f;
            po[3 * 16 + lane] = o4.w * 0.25f;
        }
    }
}

extern "C" void kernel_launch(void* const* d_in, const int* in_sizes, int n_in,
                              void* d_out, int out_size, void* d_ws, size_t ws_size,
                              hipStream_t stream) {
    const float* x   = (const float*)d_in[0];
    const int*   src = (const int*)d_in[1];
    const int*   dst = (const int*)d_in[2];
    const float* W[3]  = {(const float*)d_in[3], (const float*)d_in[7],  (const float*)d_in[11]};
    const float* al[3] = {(const float*)d_in[4], (const float*)d_in[8],  (const float*)d_in[12]};
    const float* ar[3] = {(const float*)d_in[5], (const float*)d_in[9],  (const float*)d_in[13]};
    const float* bb[3] = {(const float*)d_in[6], (const float*)d_in[10], (const float*)d_in[14]};

    size_t big = (size_t)N_NODES * HD;      // 12.8M elems
    unsigned short* featb = (unsigned short*)d_ws;
    unsigned short* hb1 = featb + big;
    unsigned short* hb2 = hb1 + big;
    float* el = (float*)(hb2 + big);
    float* er = el + (size_t)N_NODES * NHEAD;
    int* deg     = (int*)(er + (size_t)N_NODES * NHEAD);
    int* rowptr  = deg + 50048;
    int* cursor  = rowptr + 50048;
    int* csr_src = cursor + 50048;          // E ints
    int* bsum    = csr_src + N_EDGES;       // 64 ints
    unsigned short* Wp = (unsigned short*)(bsum + 64);  // 3*128*64*8

    const int NB = (N_NODES + 1023) / 1024;  // 49

    // ---- weight pack + CSR build (once per launch) ----
    packw_k<<<384, 64, 0, stream>>>(W[0], W[1], W[2], Wp);
    hipMemsetAsync(deg, 0, (size_t)N_NODES * 4, stream);
    hist_k<<<N_EDGES / 256, 256, 0, stream>>>(dst, deg);
    scan1_k<<<NB, 1024, 0, stream>>>(deg, rowptr, bsum);
    scan3_k<<<NB, 1024, 0, stream>>>(rowptr, bsum, cursor, NB);
    scatter_k<<<N_EDGES / 256, 256, 0, stream>>>(src, dst, cursor, csr_src);

    int ggrid = (N_NODES + 63) / 64;
    int agrid = (N_NODES + 3) / 4;

    gemm_k<true><<<ggrid, 256, 0, stream>>>(x, Wp, al[0], ar[0], featb, el, er, N_NODES);
    agg_k<0><<<agrid, 256, 0, stream>>>(rowptr, csr_src, el, er, featb,
                                        nullptr, bb[0], nullptr, hb1);
    gemm_k<false><<<ggrid, 256, 0, stream>>>(hb1, Wp + (size_t)1 * 128 * 64 * 8,
                                             al[1], ar[1], featb, el, er, N_NODES);
    agg_k<1><<<agrid, 256, 0, stream>>>(rowptr, csr_src, el, er, featb,
                                        hb1, bb[1], nullptr, hb2);
    gemm_k<false><<<ggrid, 256, 0, stream>>>(hb2, Wp + (size_t)2 * 128 * 64 * 8,
                                             al[2], ar[2], featb, el, er, N_NODES);
    agg_k<2><<<agrid, 256, 0, stream>>>(rowptr, csr_src, el, er, featb,
                                        hb2, bb[2], (float*)d_out, nullptr);
}

// Round 9
// 348.473 us; speedup vs baseline: 1.0290x; 1.0070x over previous
//
#include <hip/hip_runtime.h>
#include <math.h>

#define N_NODES 50000
#define N_EDGES 800000
#define HD 256      // H*D
#define NHEAD 4
#define DH 64

typedef short bf16x8 __attribute__((ext_vector_type(8)));
typedef float f32x4 __attribute__((ext_vector_type(4)));

__device__ __forceinline__ unsigned short f2bf(float f) {  // RNE
    unsigned u = __float_as_uint(f);
    return (unsigned short)((u + 0x7fffu + ((u >> 16) & 1u)) >> 16);
}
__device__ __forceinline__ float bf2f(unsigned short h) {
    return __uint_as_float((unsigned)h << 16);
}
// π: stored col c' holds original col orig(c') = (c'&~63) | ((c'&3)*16 + ((c'>>2)&15))
__device__ __forceinline__ int origk(int k) {
    return (k & ~63) | ((k & 3) * 16 + ((k >> 2) & 15));
}

// ---------- pack W into per-lane MFMA B-frag layout; also zero deg ----------
// Wp[L][nt(16)][kt(8)][lane(64)][j(8)] = W[krow][nt*16 + (lane&15)]
// krow = kt*32+(lane>>4)*8+j for L==0 (A natural); origk(...) for L>0 (A in π)
__global__ void packw_k(const float* __restrict__ W0, const float* __restrict__ W1,
                        const float* __restrict__ W2, unsigned short* __restrict__ Wp,
                        int* __restrict__ deg) {
    int blk = blockIdx.x;           // 384 = 3 layers * 128 tiles
    int L = blk >> 7, t = blk & 127;
    const float* W = L == 0 ? W0 : L == 1 ? W1 : W2;
    int nt = t >> 3, kt = t & 7;
    int lane = threadIdx.x;
    // fused deg zeroing (24576 threads, stride covers 50000)
    for (int i = blk * 64 + lane; i < N_NODES; i += 384 * 64) deg[i] = 0;
    int col = nt * 16 + (lane & 15);
    int kb = kt * 32 + (lane >> 4) * 8;
    unsigned short v[8];
#pragma unroll
    for (int j = 0; j < 8; j++) {
        int k = kb + j;
        if (L > 0) k = origk(k);
        v[j] = f2bf(W[(size_t)k * 256 + col]);
    }
    *(bf16x8*)(Wp + ((size_t)(L * 128 + t) * 64 + lane) * 8) = *(bf16x8*)v;
}

// ---------- bf16 MFMA GEMM + fused el/er epilogue; C stored in π layout ----------
template <bool AFP32>
__global__ __launch_bounds__(256) void gemm_k(const void* __restrict__ Av,
                                              const unsigned short* __restrict__ Wp,
                                              const float* __restrict__ al,
                                              const float* __restrict__ ar,
                                              unsigned short* __restrict__ C,
                                              float* __restrict__ el,
                                              float* __restrict__ er, int M) {
    __shared__ unsigned short Asl[64 * 256];   // 32KB, XOR-swizzled bf16 A-tile
    int tid = threadIdx.x, wv = tid >> 6, lane = tid & 63;
    int bm = blockIdx.x * 64;
    if (AFP32) {
        const float* A = (const float*)Av;
#pragma unroll
        for (int i = 0; i < 8; i++) {
            int chunk = i * 256 + tid;
            int r = chunk >> 5, kc = (chunk & 31) * 8;
            float4 f0, f1;
            if (bm + r < M) {
                const float* p = A + (size_t)(bm + r) * 256 + kc;
                f0 = *(const float4*)p;
                f1 = *(const float4*)(p + 4);
            } else {
                f0 = f1 = make_float4(0.f, 0.f, 0.f, 0.f);
            }
            unsigned short tmp[8] = {f2bf(f0.x), f2bf(f0.y), f2bf(f0.z), f2bf(f0.w),
                                     f2bf(f1.x), f2bf(f1.y), f2bf(f1.z), f2bf(f1.w)};
            int b = (r * 512 + kc * 2) ^ ((r & 7) << 4);
            *(bf16x8*)((char*)Asl + b) = *(bf16x8*)tmp;
        }
    } else {
        // global_load_lds: linear LDS dest, inverse-swizzled per-lane global source.
        const unsigned short* A = (const unsigned short*)Av;
#pragma unroll
        for (int i = 0; i < 8; i++) {
            int chunk = i * 256 + wv * 64 + lane;
            int r = chunk >> 5;
            int c16 = (chunk & 31) ^ (r & 7);
            const unsigned short* src = A + (size_t)(bm + r) * 256 + c16 * 8;
            __builtin_amdgcn_global_load_lds(
                (const __attribute__((address_space(1))) unsigned int*)src,
                (__attribute__((address_space(3))) unsigned int*)
                    ((char*)Asl + (size_t)(i * 256 + wv * 64) * 16),
                16, 0, 0);
        }
    }
    __syncthreads();
    f32x4 acc[4][4] = {};
    const unsigned short* wbase = Wp + (size_t)(wv * 4) * 8 * 64 * 8;  // nt base = wv*4
#pragma unroll
    for (int kk = 0; kk < 8; kk++) {
        bf16x8 a[4], b[4];
#pragma unroll
        for (int m = 0; m < 4; m++) {
            int r = m * 16 + (lane & 15);
            int kb = kk * 32 + (lane >> 4) * 8;
            int byt = (r * 512 + kb * 2) ^ ((r & 7) << 4);
            a[m] = *(const bf16x8*)((const char*)Asl + byt);
        }
#pragma unroll
        for (int n = 0; n < 4; n++)
            b[n] = *(const bf16x8*)(wbase + ((size_t)(n * 8 + kk) * 64 + lane) * 8);
#pragma unroll
        for (int m = 0; m < 4; m++)
#pragma unroll
            for (int n = 0; n < 4; n++)
                acc[m][n] = __builtin_amdgcn_mfma_f32_16x16x32_bf16(a[m], b[n],
                                                                    acc[m][n], 0, 0, 0);
    }
    int rr = lane >> 4, cc = lane & 15;
    // ---- el/er: butterfly transpose-reduce ----
    float alv[4], arv[4];
#pragma unroll
    for (int n = 0; n < 4; n++) {
        alv[n] = al[wv * 64 + n * 16 + cc];
        arv[n] = ar[wv * 64 + n * 16 + cc];
    }
    float vl[16], vr[16];
#pragma unroll
    for (int m = 0; m < 4; m++)
#pragma unroll
        for (int r = 0; r < 4; r++) {
            float ep = 0.f, rp = 0.f;
#pragma unroll
            for (int n = 0; n < 4; n++) {
                ep = fmaf(acc[m][n][r], alv[n], ep);
                rp = fmaf(acc[m][n][r], arv[n], rp);
            }
            vl[m * 4 + r] = ep;
            vr[m * 4 + r] = rp;
        }
    float l8[8], r8[8];
#pragma unroll
    for (int i = 0; i < 8; i++) {
        float xs = (cc & 1) ? vl[2 * i] : vl[2 * i + 1];
        float xk = (cc & 1) ? vl[2 * i + 1] : vl[2 * i];
        l8[i] = xk + __shfl_xor(xs, 1);
        float ys = (cc & 1) ? vr[2 * i] : vr[2 * i + 1];
        float yk = (cc & 1) ? vr[2 * i + 1] : vr[2 * i];
        r8[i] = yk + __shfl_xor(ys, 1);
    }
    float l4[4], r4[4];
#pragma unroll
    for (int i = 0; i < 4; i++) {
        float xs = (cc & 2) ? l8[2 * i] : l8[2 * i + 1];
        float xk = (cc & 2) ? l8[2 * i + 1] : l8[2 * i];
        l4[i] = xk + __shfl_xor(xs, 2);
        float ys = (cc & 2) ? r8[2 * i] : r8[2 * i + 1];
        float yk = (cc & 2) ? r8[2 * i + 1] : r8[2 * i];
        r4[i] = yk + __shfl_xor(ys, 2);
    }
    float l2[2], r2[2];
#pragma unroll
    for (int i = 0; i < 2; i++) {
        float xs = (cc & 4) ? l4[2 * i] : l4[2 * i + 1];
        float xk = (cc & 4) ? l4[2 * i + 1] : l4[2 * i];
        l2[i] = xk + __shfl_xor(xs, 4);
        float ys = (cc & 4) ? r4[2 * i] : r4[2 * i + 1];
        float yk = (cc & 4) ? r4[2 * i + 1] : r4[2 * i];
        r2[i] = yk + __shfl_xor(ys, 4);
    }
    {
        float xs = (cc & 8) ? l2[0] : l2[1];
        float xk = (cc & 8) ? l2[1] : l2[0];
        float lv = xk + __shfl_xor(xs, 8);
        float ys = (cc & 8) ? r2[0] : r2[1];
        float yk = (cc & 8) ? r2[1] : r2[0];
        float rv = yk + __shfl_xor(ys, 8);
        int row_e = bm + (cc >> 2) * 16 + rr * 4 + (cc & 3);
        if (row_e < M) {
            el[(size_t)row_e * NHEAD + wv] = lv;
            er[(size_t)row_e * NHEAD + wv] = rv;
        }
    }
    // ---- C store in π layout: lane's 4 cols contiguous (8B coalesced) ----
#pragma unroll
    for (int m = 0; m < 4; m++) {
#pragma unroll
        for (int r = 0; r < 4; r++) {
            int row = bm + m * 16 + rr * 4 + r;
            if (row < M) {
                unsigned short p4[4] = {f2bf(acc[m][0][r]), f2bf(acc[m][1][r]),
                                        f2bf(acc[m][2][r]), f2bf(acc[m][3][r])};
                *(ushort4*)(C + (size_t)row * 256 + wv * 64 + cc * 4) = *(ushort4*)p4;
            }
        }
    }
}

// ---------- CSR build ----------
__global__ void hist_k(const int* __restrict__ dst, int* __restrict__ deg) {
    int e = (blockIdx.x * 256 + threadIdx.x) * 2;
    if (e + 1 < N_EDGES) {
        int2 d2 = *(const int2*)(dst + e);
        atomicAdd(&deg[d2.x], 1);
        atomicAdd(&deg[d2.y], 1);
    } else if (e < N_EDGES) {
        atomicAdd(&deg[dst[e]], 1);
    }
}

__global__ __launch_bounds__(1024) void scan1_k(const int* __restrict__ deg,
                                                int* __restrict__ rowptr,
                                                int* __restrict__ bsum) {
    __shared__ int wsum[16];
    int tid = threadIdx.x, lane = tid & 63, wv = tid >> 6;
    int i = blockIdx.x * 1024 + tid;
    int v = (i < N_NODES) ? deg[i] : 0;
    int sc = v;
#pragma unroll
    for (int o = 1; o < 64; o <<= 1) {
        int t = __shfl_up(sc, o);
        if (lane >= o) sc += t;
    }
    if (lane == 63) wsum[wv] = sc;
    __syncthreads();
    if (wv == 0 && lane < 16) {
        int ws = wsum[lane];
#pragma unroll
        for (int o = 1; o < 16; o <<= 1) {
            int t = __shfl_up(ws, o);
            if (lane >= o) ws += t;
        }
        wsum[lane] = ws;
    }
    __syncthreads();
    int incl = sc + (wv > 0 ? wsum[wv - 1] : 0);
    if (i < N_NODES) rowptr[i + 1] = incl;
    if (tid == 1023) bsum[blockIdx.x] = incl;
}

__global__ __launch_bounds__(1024) void scan3_k(int* __restrict__ rowptr,
                                                const int* __restrict__ bsum,
                                                int* __restrict__ cursor, int nb) {
    __shared__ int boff_s;
    int tid = threadIdx.x;
    if (tid < 64) {
        int v = (tid < nb) ? bsum[tid] : 0;
        int sc = v;
#pragma unroll
        for (int o = 1; o < 64; o <<= 1) {
            int t = __shfl_up(sc, o);
            if ((tid & 63) >= o) sc += t;
        }
        if (tid == (int)blockIdx.x) boff_s = sc - v;  // exclusive prefix
    }
    __syncthreads();
    int off = boff_s;
    int i = blockIdx.x * 1024 + tid;
    if (blockIdx.x == 0 && tid == 0) { rowptr[0] = 0; cursor[0] = 0; }
    if (i < N_NODES) {
        int v = rowptr[i + 1] + off;
        rowptr[i + 1] = v;
        if (i + 1 < N_NODES) cursor[i + 1] = v;
    }
}

__global__ void scatter_k(const int* __restrict__ src, const int* __restrict__ dst,
                          int* __restrict__ cursor, int* __restrict__ csr_src) {
    int e = blockIdx.x * 256 + threadIdx.x;
    if (e >= N_EDGES) return;
    int pos = atomicAdd(&cursor[dst[e]], 1);
    csr_src[pos] = src[e];
}

// ---------- fused per-dst softmax (max-free) + gather-aggregate + epilogue ----------
// feat/resid/hb in π layout. MODE 0: no resid, ELU; MODE 1: resid, ELU;
// MODE 2: resid, no act, head-mean, fp32 out (unpermuted)
template <int MODE>
__global__ __launch_bounds__(256) void agg_k(const int* __restrict__ rowptr,
                                             const int* __restrict__ csr_src,
                                             const float* __restrict__ el,
                                             const float* __restrict__ er,
                                             const unsigned short* __restrict__ feat,
                                             const unsigned short* __restrict__ resid,
                                             const float* __restrict__ bias,
                                             float* __restrict__ out,
                                             unsigned short* __restrict__ hb) {
    __shared__ int   ws_s[4][64];       // byte offsets s*512
    __shared__ float ws_w[4][4][68];    // [wave][head][edge], pad 68 de-banks
    int wv = threadIdx.x >> 6, lane = threadIdx.x & 63;
    int node = blockIdx.x * 4 + wv;
    if (node >= N_NODES) return;
    int beg = rowptr[node], end = rowptr[node + 1];
    float4 er4 = *(const float4*)(er + (size_t)node * 4);
    float4 acc0 = make_float4(0.f, 0.f, 0.f, 0.f);
    float4 acc1 = make_float4(0.f, 0.f, 0.f, 0.f);
    float4 den = make_float4(0.f, 0.f, 0.f, 0.f);
    int h = lane >> 4;
    int l8 = lane * 8;
    const char* fb = (const char*)feat;
    for (int base = beg; base < end; base += 64) {
        int j = base + lane;
        int soff = 0;
        float4 w = make_float4(0.f, 0.f, 0.f, 0.f);
        if (j < end) {
            int s = csr_src[j];
            soff = s << 9;              // byte offset of feat row (256 bf16)
            float4 l4 = *(const float4*)(el + (size_t)s * 4);
            float vx = l4.x + er4.x; vx = vx > 0.f ? vx : 0.2f * vx;
            float vy = l4.y + er4.y; vy = vy > 0.f ? vy : 0.2f * vy;
            float vz = l4.z + er4.z; vz = vz > 0.f ? vz : 0.2f * vz;
            float vw = l4.w + er4.w; vw = vw > 0.f ? vw : 0.2f * vw;
            // max-free softmax: |v| = O(3), exp cannot overflow fp32
            w.x = expf(vx); w.y = expf(vy); w.z = expf(vz); w.w = expf(vw);
            den.x += w.x; den.y += w.y; den.z += w.z; den.w += w.w;
        }
        ws_s[wv][lane] = soff;          // dummy lanes: soff=0, w=0
        ws_w[wv][0][lane] = w.x;
        ws_w[wv][1][lane] = w.y;
        ws_w[wv][2][lane] = w.z;
        ws_w[wv][3][lane] = w.w;
        __builtin_amdgcn_wave_barrier();
        int cnt = end - base; if (cnt > 64) cnt = 64;
        int cnt8 = (cnt + 7) & ~7;      // zero-padded: no tail loop
        for (int k = 0; k < cnt8; k += 8) {
            int4   soA = *(const int4*)&ws_s[wv][k];
            int4   soB = *(const int4*)&ws_s[wv][k + 4];
            float4 wA = *(const float4*)&ws_w[wv][h][k];
            float4 wB = *(const float4*)&ws_w[wv][h][k + 4];
            ushort4 u0 = *(const ushort4*)(fb + (soA.x + l8));
            ushort4 u1 = *(const ushort4*)(fb + (soA.y + l8));
            ushort4 u2 = *(const ushort4*)(fb + (soA.z + l8));
            ushort4 u3 = *(const ushort4*)(fb + (soA.w + l8));
            ushort4 u4 = *(const ushort4*)(fb + (soB.x + l8));
            ushort4 u5 = *(const ushort4*)(fb + (soB.y + l8));
            ushort4 u6 = *(const ushort4*)(fb + (soB.z + l8));
            ushort4 u7 = *(const ushort4*)(fb + (soB.w + l8));
            acc0.x = fmaf(wA.x, bf2f(u0.x), acc0.x);
            acc0.y = fmaf(wA.x, bf2f(u0.y), acc0.y);
            acc0.z = fmaf(wA.x, bf2f(u0.z), acc0.z);
            acc0.w = fmaf(wA.x, bf2f(u0.w), acc0.w);
            acc1.x = fmaf(wA.y, bf2f(u1.x), acc1.x);
            acc1.y = fmaf(wA.y, bf2f(u1.y), acc1.y);
            acc1.z = fmaf(wA.y, bf2f(u1.z), acc1.z);
            acc1.w = fmaf(wA.y, bf2f(u1.w), acc1.w);
            acc0.x = fmaf(wA.z, bf2f(u2.x), acc0.x);
            acc0.y = fmaf(wA.z, bf2f(u2.y), acc0.y);
            acc0.z = fmaf(wA.z, bf2f(u2.z), acc0.z);
            acc0.w = fmaf(wA.z, bf2f(u2.w), acc0.w);
            acc1.x = fmaf(wA.w, bf2f(u3.x), acc1.x);
            acc1.y = fmaf(wA.w, bf2f(u3.y), acc1.y);
            acc1.z = fmaf(wA.w, bf2f(u3.z), acc1.z);
            acc1.w = fmaf(wA.w, bf2f(u3.w), acc1.w);
            acc0.x = fmaf(wB.x, bf2f(u4.x), acc0.x);
            acc0.y = fmaf(wB.x, bf2f(u4.y), acc0.y);
            acc0.z = fmaf(wB.x, bf2f(u4.z), acc0.z);
            acc0.w = fmaf(wB.x, bf2f(u4.w), acc0.w);
            acc1.x = fmaf(wB.y, bf2f(u5.x), acc1.x);
            acc1.y = fmaf(wB.y, bf2f(u5.y), acc1.y);
            acc1.z = fmaf(wB.y, bf2f(u5.z), acc1.z);
            acc1.w = fmaf(wB.y, bf2f(u5.w), acc1.w);
            acc0.x = fmaf(wB.z, bf2f(u6.x), acc0.x);
            acc0.y = fmaf(wB.z, bf2f(u6.y), acc0.y);
            acc0.z = fmaf(wB.z, bf2f(u6.z), acc0.z);
            acc0.w = fmaf(wB.z, bf2f(u6.w), acc0.w);
            acc1.x = fmaf(wB.w, bf2f(u7.x), acc1.x);
            acc1.y = fmaf(wB.w, bf2f(u7.y), acc1.y);
            acc1.z = fmaf(wB.w, bf2f(u7.z), acc1.z);
            acc1.w = fmaf(wB.w, bf2f(u7.w), acc1.w);
        }
        __builtin_amdgcn_wave_barrier();
    }
    float4 acc;
    acc.x = acc0.x + acc1.x; acc.y = acc0.y + acc1.y;
    acc.z = acc0.z + acc1.z; acc.w = acc0.w + acc1.w;
#pragma unroll
    for (int o = 1; o < 64; o <<= 1) {
        den.x += __shfl_xor(den.x, o);
        den.y += __shfl_xor(den.y, o);
        den.z += __shfl_xor(den.z, o);
        den.w += __shfl_xor(den.w, o);
    }
    float den_me = h == 0 ? den.x : h == 1 ? den.y : h == 2 ? den.z : den.w;
    float r = den_me > 0.f ? 1.f / den_me : 0.f;
    int cc = lane & 15;
    float4 b4;
    b4.x = bias[h * 64 + 0 * 16 + cc];
    b4.y = bias[h * 64 + 1 * 16 + cc];
    b4.z = bias[h * 64 + 2 * 16 + cc];
    b4.w = bias[h * 64 + 3 * 16 + cc];
    float4 o4;
    o4.x = acc.x * r + b4.x;
    o4.y = acc.y * r + b4.y;
    o4.z = acc.z * r + b4.z;
    o4.w = acc.w * r + b4.w;
    if (MODE >= 1) {
        ushort4 r4 = *(const ushort4*)(resid + (size_t)node * HD + lane * 4);
        o4.x += bf2f(r4.x); o4.y += bf2f(r4.y);
        o4.z += bf2f(r4.z); o4.w += bf2f(r4.w);
    }
    if (MODE <= 1) {
        o4.x = o4.x > 0.f ? o4.x : expm1f(o4.x);
        o4.y = o4.y > 0.f ? o4.y : expm1f(o4.y);
        o4.z = o4.z > 0.f ? o4.z : expm1f(o4.z);
        o4.w = o4.w > 0.f ? o4.w : expm1f(o4.w);
        ushort4 hv;
        hv.x = f2bf(o4.x); hv.y = f2bf(o4.y); hv.z = f2bf(o4.z); hv.w = f2bf(o4.w);
        *(ushort4*)(hb + (size_t)node * HD + lane * 4) = hv;
    } else {
        o4.x += __shfl_xor(o4.x, 16); o4.x += __shfl_xor(o4.x, 32);
        o4.y += __shfl_xor(o4.y, 16); o4.y += __shfl_xor(o4.y, 32);
        o4.z += __shfl_xor(o4.z, 16); o4.z += __shfl_xor(o4.z, 32);
        o4.w += __shfl_xor(o4.w, 16); o4.w += __shfl_xor(o4.w, 32);
        if (lane < 16) {
            float* po = out + (size_t)node * DH;
            po[0 * 16 + lane] = o4.x * 0.25f;
            po[1 * 16 + lane] = o4.y * 0.25f;
            po[2 * 16 + lane] = o4.z * 0.25f;
            po[3 * 16 + lane] = o4.w * 0.25f;
        }
    }
}

extern "C" void kernel_launch(void* const* d_in, const int* in_sizes, int n_in,
                              void* d_out, int out_size, void* d_ws, size_t ws_size,
                              hipStream_t stream) {
    const float* x   = (const float*)d_in[0];
    const int*   src = (const int*)d_in[1];
    const int*   dst = (const int*)d_in[2];
    const float* W[3]  = {(const float*)d_in[3], (const float*)d_in[7],  (const float*)d_in[11]};
    const float* al[3] = {(const float*)d_in[4], (const float*)d_in[8],  (const float*)d_in[12]};
    const float* ar[3] = {(const float*)d_in[5], (const float*)d_in[9],  (const float*)d_in[13]};
    const float* bb[3] = {(const float*)d_in[6], (const float*)d_in[10], (const float*)d_in[14]};

    size_t big = (size_t)N_NODES * HD;      // 12.8M elems
    unsigned short* featb = (unsigned short*)d_ws;
    unsigned short* hb1 = featb + big;
    unsigned short* hb2 = hb1 + big;
    float* el = (float*)(hb2 + big);
    float* er = el + (size_t)N_NODES * NHEAD;
    int* deg     = (int*)(er + (size_t)N_NODES * NHEAD);
    int* rowptr  = deg + 50048;
    int* cursor  = rowptr + 50048;
    int* csr_src = cursor + 50048;          // E ints
    int* bsum    = csr_src + N_EDGES;       // 64 ints
    unsigned short* Wp = (unsigned short*)(bsum + 64);  // 3*128*64*8

    const int NB = (N_NODES + 1023) / 1024;  // 49

    // ---- weight pack (+deg zero) + CSR build (once per launch) ----
    packw_k<<<384, 64, 0, stream>>>(W[0], W[1], W[2], Wp, deg);
    hist_k<<<(N_EDGES / 2 + 255) / 256, 256, 0, stream>>>(dst, deg);
    scan1_k<<<NB, 1024, 0, stream>>>(deg, rowptr, bsum);
    scan3_k<<<NB, 1024, 0, stream>>>(rowptr, bsum, cursor, NB);
    scatter_k<<<N_EDGES / 256, 256, 0, stream>>>(src, dst, cursor, csr_src);

    int ggrid = (N_NODES + 63) / 64;
    int agrid = (N_NODES + 3) / 4;

    gemm_k<true><<<ggrid, 256, 0, stream>>>(x, Wp, al[0], ar[0], featb, el, er, N_NODES);
    agg_k<0><<<agrid, 256, 0, stream>>>(rowptr, csr_src, el, er, featb,
                                        nullptr, bb[0], nullptr, hb1);
    gemm_k<false><<<ggrid, 256, 0, stream>>>(hb1, Wp + (size_t)1 * 128 * 64 * 8,
                                             al[1], ar[1], featb, el, er, N_NODES);
    agg_k<1><<<agrid, 256, 0, stream>>>(rowptr, csr_src, el, er, featb,
                                        hb1, bb[1], nullptr, hb2);
    gemm_k<false><<<ggrid, 256, 0, stream>>>(hb2, Wp + (size_t)2 * 128 * 64 * 8,
                                             al[2], ar[2], featb, el, er, N_NODES);
    agg_k<2><<<agrid, 256, 0, stream>>>(rowptr, csr_src, el, er, featb,
                                        hb2, bb[2], (float*)d_out, nullptr);
}

// Round 10
// 340.016 us; speedup vs baseline: 1.0546x; 1.0249x over previous
//
#include <hip/hip_runtime.h>
#include <math.h>

#define N_NODES 50000
#define N_EDGES 800000
#define HD 256      // H*D
#define NHEAD 4
#define DH 64

typedef short bf16x8 __attribute__((ext_vector_type(8)));
typedef float f32x4 __attribute__((ext_vector_type(4)));

__device__ __forceinline__ unsigned short f2bf(float f) {  // RNE
    unsigned u = __float_as_uint(f);
    return (unsigned short)((u + 0x7fffu + ((u >> 16) & 1u)) >> 16);
}
__device__ __forceinline__ float bf2f(unsigned short h) {
    return __uint_as_float((unsigned)h << 16);
}
// π: stored col c' holds original col orig(c') = (c'&~63) | ((c'&3)*16 + ((c'>>2)&15))
__device__ __forceinline__ int origk(int k) {
    return (k & ~63) | ((k & 3) * 16 + ((k >> 2) & 15));
}

// ---------- pack W into per-lane MFMA B-frag layout; also zero deg ----------
__global__ void packw_k(const float* __restrict__ W0, const float* __restrict__ W1,
                        const float* __restrict__ W2, unsigned short* __restrict__ Wp,
                        int* __restrict__ deg) {
    int blk = blockIdx.x;           // 384 = 3 layers * 128 tiles
    int L = blk >> 7, t = blk & 127;
    const float* W = L == 0 ? W0 : L == 1 ? W1 : W2;
    int nt = t >> 3, kt = t & 7;
    int lane = threadIdx.x;
    for (int i = blk * 64 + lane; i < N_NODES; i += 384 * 64) deg[i] = 0;
    int col = nt * 16 + (lane & 15);
    int kb = kt * 32 + (lane >> 4) * 8;
    unsigned short v[8];
#pragma unroll
    for (int j = 0; j < 8; j++) {
        int k = kb + j;
        if (L > 0) k = origk(k);
        v[j] = f2bf(W[(size_t)k * 256 + col]);
    }
    *(bf16x8*)(Wp + ((size_t)(L * 128 + t) * 64 + lane) * 8) = *(bf16x8*)v;
}

// ---------- shared GEMM pieces ----------
__device__ __forceinline__ void mfma_tile(const unsigned short* Asl,
                                          const unsigned short* wbase,
                                          int lane, f32x4 acc[4][4]) {
#pragma unroll
    for (int kk = 0; kk < 8; kk++) {
        bf16x8 a[4], b[4];
#pragma unroll
        for (int m = 0; m < 4; m++) {
            int r = m * 16 + (lane & 15);
            int kb = kk * 32 + (lane >> 4) * 8;
            int byt = (r * 512 + kb * 2) ^ ((r & 7) << 4);
            a[m] = *(const bf16x8*)((const char*)Asl + byt);
        }
#pragma unroll
        for (int n = 0; n < 4; n++)
            b[n] = *(const bf16x8*)(wbase + ((size_t)(n * 8 + kk) * 64 + lane) * 8);
#pragma unroll
        for (int m = 0; m < 4; m++)
#pragma unroll
            for (int n = 0; n < 4; n++)
                acc[m][n] = __builtin_amdgcn_mfma_f32_16x16x32_bf16(a[m], b[n],
                                                                    acc[m][n], 0, 0, 0);
    }
}

// el/er butterfly + π-layout C store
__device__ __forceinline__ void epilogue_tile(f32x4 acc[4][4], int bm, int wv, int lane,
                                              const float* __restrict__ al,
                                              const float* __restrict__ ar,
                                              unsigned short* __restrict__ C,
                                              float* __restrict__ el,
                                              float* __restrict__ er, int M) {
    int rr = lane >> 4, cc = lane & 15;
    float alv[4], arv[4];
#pragma unroll
    for (int n = 0; n < 4; n++) {
        alv[n] = al[wv * 64 + n * 16 + cc];
        arv[n] = ar[wv * 64 + n * 16 + cc];
    }
    float vl[16], vr[16];
#pragma unroll
    for (int m = 0; m < 4; m++)
#pragma unroll
        for (int r = 0; r < 4; r++) {
            float ep = 0.f, rp = 0.f;
#pragma unroll
            for (int n = 0; n < 4; n++) {
                ep = fmaf(acc[m][n][r], alv[n], ep);
                rp = fmaf(acc[m][n][r], arv[n], rp);
            }
            vl[m * 4 + r] = ep;
            vr[m * 4 + r] = rp;
        }
    float l8[8], r8[8];
#pragma unroll
    for (int i = 0; i < 8; i++) {
        float xs = (cc & 1) ? vl[2 * i] : vl[2 * i + 1];
        float xk = (cc & 1) ? vl[2 * i + 1] : vl[2 * i];
        l8[i] = xk + __shfl_xor(xs, 1);
        float ys = (cc & 1) ? vr[2 * i] : vr[2 * i + 1];
        float yk = (cc & 1) ? vr[2 * i + 1] : vr[2 * i];
        r8[i] = yk + __shfl_xor(ys, 1);
    }
    float l4[4], r4[4];
#pragma unroll
    for (int i = 0; i < 4; i++) {
        float xs = (cc & 2) ? l8[2 * i] : l8[2 * i + 1];
        float xk = (cc & 2) ? l8[2 * i + 1] : l8[2 * i];
        l4[i] = xk + __shfl_xor(xs, 2);
        float ys = (cc & 2) ? r8[2 * i] : r8[2 * i + 1];
        float yk = (cc & 2) ? r8[2 * i + 1] : r8[2 * i];
        r4[i] = yk + __shfl_xor(ys, 2);
    }
    float l2[2], r2[2];
#pragma unroll
    for (int i = 0; i < 2; i++) {
        float xs = (cc & 4) ? l4[2 * i] : l4[2 * i + 1];
        float xk = (cc & 4) ? l4[2 * i + 1] : l4[2 * i];
        l2[i] = xk + __shfl_xor(xs, 4);
        float ys = (cc & 4) ? r4[2 * i] : r4[2 * i + 1];
        float yk = (cc & 4) ? r4[2 * i + 1] : r4[2 * i];
        r2[i] = yk + __shfl_xor(ys, 4);
    }
    {
        float xs = (cc & 8) ? l2[0] : l2[1];
        float xk = (cc & 8) ? l2[1] : l2[0];
        float lv = xk + __shfl_xor(xs, 8);
        float ys = (cc & 8) ? r2[0] : r2[1];
        float yk = (cc & 8) ? r2[1] : r2[0];
        float rv = yk + __shfl_xor(ys, 8);
        int row_e = bm + (cc >> 2) * 16 + rr * 4 + (cc & 3);
        if (row_e < M) {
            el[(size_t)row_e * NHEAD + wv] = lv;
            er[(size_t)row_e * NHEAD + wv] = rv;
        }
    }
#pragma unroll
    for (int m = 0; m < 4; m++) {
#pragma unroll
        for (int r = 0; r < 4; r++) {
            int row = bm + m * 16 + rr * 4 + r;
            if (row < M) {
                unsigned short p4[4] = {f2bf(acc[m][0][r]), f2bf(acc[m][1][r]),
                                        f2bf(acc[m][2][r]), f2bf(acc[m][3][r])};
                *(ushort4*)(C + (size_t)row * 256 + wv * 64 + cc * 4) = *(ushort4*)p4;
            }
        }
    }
}

// ---------- layer-0 GEMM: fp32 A, 1 tile/block ----------
__global__ __launch_bounds__(256) void gemm0_k(const float* __restrict__ A,
                                               const unsigned short* __restrict__ Wp,
                                               const float* __restrict__ al,
                                               const float* __restrict__ ar,
                                               unsigned short* __restrict__ C,
                                               float* __restrict__ el,
                                               float* __restrict__ er, int M) {
    __shared__ unsigned short Asl[64 * 256];
    int tid = threadIdx.x, wv = tid >> 6, lane = tid & 63;
    int bm = blockIdx.x * 64;
#pragma unroll
    for (int i = 0; i < 8; i++) {
        int chunk = i * 256 + tid;
        int r = chunk >> 5, kc = (chunk & 31) * 8;
        float4 f0, f1;
        if (bm + r < M) {
            const float* p = A + (size_t)(bm + r) * 256 + kc;
            f0 = *(const float4*)p;
            f1 = *(const float4*)(p + 4);
        } else {
            f0 = f1 = make_float4(0.f, 0.f, 0.f, 0.f);
        }
        unsigned short tmp[8] = {f2bf(f0.x), f2bf(f0.y), f2bf(f0.z), f2bf(f0.w),
                                 f2bf(f1.x), f2bf(f1.y), f2bf(f1.z), f2bf(f1.w)};
        int b = (r * 512 + kc * 2) ^ ((r & 7) << 4);
        *(bf16x8*)((char*)Asl + b) = *(bf16x8*)tmp;
    }
    __syncthreads();
    const unsigned short* wbase = Wp + (size_t)(wv * 4) * 8 * 64 * 8;
    f32x4 acc[4][4] = {};
    mfma_tile(Asl, wbase, lane, acc);
    epilogue_tile(acc, bm, wv, lane, al, ar, C, el, er, M);
}

// ---------- layers 1/2 GEMM: bf16 A, 2 tiles/block, async dbuf (counted vmcnt) ----------
__global__ __launch_bounds__(256) void gemm2_k(const unsigned short* __restrict__ A,
                                               const unsigned short* __restrict__ Wp,
                                               const float* __restrict__ al,
                                               const float* __restrict__ ar,
                                               unsigned short* __restrict__ C,
                                               float* __restrict__ el,
                                               float* __restrict__ er, int M) {
    __shared__ unsigned short Asl[2][64 * 256];   // 64 KB
    int tid = threadIdx.x, wv = tid >> 6, lane = tid & 63;
    int bm0 = blockIdx.x * 128, bm1 = bm0 + 64;
    // issue BOTH tiles' async stages; inverse-swizzled source, linear LDS dest
#pragma unroll
    for (int i = 0; i < 8; i++) {
        int chunk = i * 256 + tid;
        int r = chunk >> 5;
        int c16 = (chunk & 31) ^ (r & 7);
        int grow = bm0 + r; if (grow >= M) grow = M - 1;
        __builtin_amdgcn_global_load_lds(
            (const __attribute__((address_space(1))) unsigned int*)
                (A + (size_t)grow * 256 + c16 * 8),
            (__attribute__((address_space(3))) unsigned int*)
                ((char*)Asl[0] + (size_t)chunk * 16),
            16, 0, 0);
    }
#pragma unroll
    for (int i = 0; i < 8; i++) {
        int chunk = i * 256 + tid;
        int r = chunk >> 5;
        int c16 = (chunk & 31) ^ (r & 7);
        int grow = bm1 + r; if (grow >= M) grow = M - 1;
        __builtin_amdgcn_global_load_lds(
            (const __attribute__((address_space(1))) unsigned int*)
                (A + (size_t)grow * 256 + c16 * 8),
            (__attribute__((address_space(3))) unsigned int*)
                ((char*)Asl[1] + (size_t)chunk * 16),
            16, 0, 0);
    }
    asm volatile("s_waitcnt vmcnt(8)" ::: "memory");   // tile0 landed; tile1 in flight
    __builtin_amdgcn_sched_barrier(0);
    __builtin_amdgcn_s_barrier();
    const unsigned short* wbase = Wp + (size_t)(wv * 4) * 8 * 64 * 8;
    f32x4 acc[4][4] = {};
    mfma_tile(Asl[0], wbase, lane, acc);
    asm volatile("s_waitcnt vmcnt(0)" ::: "memory");   // tile1 landed (long since)
    __builtin_amdgcn_sched_barrier(0);
    __builtin_amdgcn_s_barrier();
    epilogue_tile(acc, bm0, wv, lane, al, ar, C, el, er, M);  // stores overlap tile1 compute
    f32x4 acc2[4][4] = {};
    mfma_tile(Asl[1], wbase, lane, acc2);
    epilogue_tile(acc2, bm1, wv, lane, al, ar, C, el, er, M);
}

// ---------- CSR build ----------
__global__ void hist_k(const int* __restrict__ dst, int* __restrict__ deg) {
    int e = (blockIdx.x * 256 + threadIdx.x) * 2;
    if (e + 1 < N_EDGES) {
        int2 d2 = *(const int2*)(dst + e);
        atomicAdd(&deg[d2.x], 1);
        atomicAdd(&deg[d2.y], 1);
    } else if (e < N_EDGES) {
        atomicAdd(&deg[dst[e]], 1);
    }
}

__global__ __launch_bounds__(1024) void scan1_k(const int* __restrict__ deg,
                                                int* __restrict__ rowptr,
                                                int* __restrict__ bsum) {
    __shared__ int wsum[16];
    int tid = threadIdx.x, lane = tid & 63, wv = tid >> 6;
    int i = blockIdx.x * 1024 + tid;
    int v = (i < N_NODES) ? deg[i] : 0;
    int sc = v;
#pragma unroll
    for (int o = 1; o < 64; o <<= 1) {
        int t = __shfl_up(sc, o);
        if (lane >= o) sc += t;
    }
    if (lane == 63) wsum[wv] = sc;
    __syncthreads();
    if (wv == 0 && lane < 16) {
        int ws = wsum[lane];
#pragma unroll
        for (int o = 1; o < 16; o <<= 1) {
            int t = __shfl_up(ws, o);
            if (lane >= o) ws += t;
        }
        wsum[lane] = ws;
    }
    __syncthreads();
    int incl = sc + (wv > 0 ? wsum[wv - 1] : 0);
    if (i < N_NODES) rowptr[i + 1] = incl;
    if (tid == 1023) bsum[blockIdx.x] = incl;
}

__global__ __launch_bounds__(1024) void scan3_k(int* __restrict__ rowptr,
                                                const int* __restrict__ bsum,
                                                int* __restrict__ cursor, int nb) {
    __shared__ int boff_s;
    int tid = threadIdx.x;
    if (tid < 64) {
        int v = (tid < nb) ? bsum[tid] : 0;
        int sc = v;
#pragma unroll
        for (int o = 1; o < 64; o <<= 1) {
            int t = __shfl_up(sc, o);
            if ((tid & 63) >= o) sc += t;
        }
        if (tid == (int)blockIdx.x) boff_s = sc - v;  // exclusive prefix
    }
    __syncthreads();
    int off = boff_s;
    int i = blockIdx.x * 1024 + tid;
    if (blockIdx.x == 0 && tid == 0) { rowptr[0] = 0; cursor[0] = 0; }
    if (i < N_NODES) {
        int v = rowptr[i + 1] + off;
        rowptr[i + 1] = v;
        if (i + 1 < N_NODES) cursor[i + 1] = v;
    }
}

__global__ void scatter_k(const int* __restrict__ src, const int* __restrict__ dst,
                          int* __restrict__ cursor, int* __restrict__ csr_src) {
    int e = (blockIdx.x * 256 + threadIdx.x) * 2;
    if (e + 1 < N_EDGES) {
        int2 s2 = *(const int2*)(src + e);
        int2 d2 = *(const int2*)(dst + e);
        csr_src[atomicAdd(&cursor[d2.x], 1)] = s2.x;
        csr_src[atomicAdd(&cursor[d2.y], 1)] = s2.y;
    } else if (e < N_EDGES) {
        csr_src[atomicAdd(&cursor[dst[e]], 1)] = src[e];
    }
}

// ---------- fused per-dst softmax (max-free) + gather-aggregate + epilogue ----------
// feat/resid/hb in π layout. MODE 0: no resid, ELU; MODE 1: resid, ELU;
// MODE 2: resid, no act, head-mean, fp32 out (unpermuted)
template <int MODE>
__global__ __launch_bounds__(256) void agg_k(const int* __restrict__ rowptr,
                                             const int* __restrict__ csr_src,
                                             const float* __restrict__ el,
                                             const float* __restrict__ er,
                                             const unsigned short* __restrict__ feat,
                                             const unsigned short* __restrict__ resid,
                                             const float* __restrict__ bias,
                                             float* __restrict__ out,
                                             unsigned short* __restrict__ hb) {
    __shared__ int   ws_s[4][64];       // byte offsets s*512
    __shared__ float ws_w[4][4][68];    // [wave][head][edge], pad 68 de-banks
    int wv = threadIdx.x >> 6, lane = threadIdx.x & 63;
    int node = blockIdx.x * 4 + wv;
    if (node >= N_NODES) return;
    int beg = rowptr[node], end = rowptr[node + 1];
    float4 er4 = *(const float4*)(er + (size_t)node * 4);
    float4 acc0 = make_float4(0.f, 0.f, 0.f, 0.f);
    float4 acc1 = make_float4(0.f, 0.f, 0.f, 0.f);
    float4 den = make_float4(0.f, 0.f, 0.f, 0.f);
    int h = lane >> 4;
    int l8 = lane * 8;
    const char* fb = (const char*)feat;
    for (int base = beg; base < end; base += 64) {
        int j = base + lane;
        int soff = 0;
        float4 w = make_float4(0.f, 0.f, 0.f, 0.f);
        if (j < end) {
            int s = csr_src[j];
            soff = s << 9;              // byte offset of feat row (256 bf16)
            float4 l4 = *(const float4*)(el + (size_t)s * 4);
            float vx = l4.x + er4.x; vx = vx > 0.f ? vx : 0.2f * vx;
            float vy = l4.y + er4.y; vy = vy > 0.f ? vy : 0.2f * vy;
            float vz = l4.z + er4.z; vz = vz > 0.f ? vz : 0.2f * vz;
            float vw = l4.w + er4.w; vw = vw > 0.f ? vw : 0.2f * vw;
            // max-free softmax: |v| = O(3), exp cannot overflow fp32
            w.x = expf(vx); w.y = expf(vy); w.z = expf(vz); w.w = expf(vw);
            den.x += w.x; den.y += w.y; den.z += w.z; den.w += w.w;
        }
        ws_s[wv][lane] = soff;          // dummy lanes: soff=0, w=0
        ws_w[wv][0][lane] = w.x;
        ws_w[wv][1][lane] = w.y;
        ws_w[wv][2][lane] = w.z;
        ws_w[wv][3][lane] = w.w;
        __builtin_amdgcn_wave_barrier();
        int cnt = end - base; if (cnt > 64) cnt = 64;
        int cnt4 = (cnt + 3) & ~3;      // zero-padded: no tail loop
        for (int k = 0; k < cnt4; k += 4) {
            int4   so = *(const int4*)&ws_s[wv][k];      // broadcast
            float4 w4 = *(const float4*)&ws_w[wv][h][k];
            ushort4 u0 = *(const ushort4*)(fb + (so.x + l8));
            ushort4 u1 = *(const ushort4*)(fb + (so.y + l8));
            ushort4 u2 = *(const ushort4*)(fb + (so.z + l8));
            ushort4 u3 = *(const ushort4*)(fb + (so.w + l8));
            acc0.x = fmaf(w4.x, bf2f(u0.x), acc0.x);
            acc0.y = fmaf(w4.x, bf2f(u0.y), acc0.y);
            acc0.z = fmaf(w4.x, bf2f(u0.z), acc0.z);
            acc0.w = fmaf(w4.x, bf2f(u0.w), acc0.w);
            acc1.x = fmaf(w4.y, bf2f(u1.x), acc1.x);
            acc1.y = fmaf(w4.y, bf2f(u1.y), acc1.y);
            acc1.z = fmaf(w4.y, bf2f(u1.z), acc1.z);
            acc1.w = fmaf(w4.y, bf2f(u1.w), acc1.w);
            acc0.x = fmaf(w4.z, bf2f(u2.x), acc0.x);
            acc0.y = fmaf(w4.z, bf2f(u2.y), acc0.y);
            acc0.z = fmaf(w4.z, bf2f(u2.z), acc0.z);
            acc0.w = fmaf(w4.z, bf2f(u2.w), acc0.w);
            acc1.x = fmaf(w4.w, bf2f(u3.x), acc1.x);
            acc1.y = fmaf(w4.w, bf2f(u3.y), acc1.y);
            acc1.z = fmaf(w4.w, bf2f(u3.z), acc1.z);
            acc1.w = fmaf(w4.w, bf2f(u3.w), acc1.w);
        }
        __builtin_amdgcn_wave_barrier();
    }
    float4 acc;
    acc.x = acc0.x + acc1.x; acc.y = acc0.y + acc1.y;
    acc.z = acc0.z + acc1.z; acc.w = acc0.w + acc1.w;
#pragma unroll
    for (int o = 1; o < 64; o <<= 1) {
        den.x += __shfl_xor(den.x, o);
        den.y += __shfl_xor(den.y, o);
        den.z += __shfl_xor(den.z, o);
        den.w += __shfl_xor(den.w, o);
    }
    float den_me = h == 0 ? den.x : h == 1 ? den.y : h == 2 ? den.z : den.w;
    float r = den_me > 0.f ? 1.f / den_me : 0.f;
    int cc = lane & 15;
    float4 b4;
    b4.x = bias[h * 64 + 0 * 16 + cc];
    b4.y = bias[h * 64 + 1 * 16 + cc];
    b4.z = bias[h * 64 + 2 * 16 + cc];
    b4.w = bias[h * 64 + 3 * 16 + cc];
    float4 o4;
    o4.x = acc.x * r + b4.x;
    o4.y = acc.y * r + b4.y;
    o4.z = acc.z * r + b4.z;
    o4.w = acc.w * r + b4.w;
    if (MODE >= 1) {
        ushort4 r4 = *(const ushort4*)(resid + (size_t)node * HD + lane * 4);
        o4.x += bf2f(r4.x); o4.y += bf2f(r4.y);
        o4.z += bf2f(r4.z); o4.w += bf2f(r4.w);
    }
    if (MODE <= 1) {
        o4.x = o4.x > 0.f ? o4.x : expm1f(o4.x);
        o4.y = o4.y > 0.f ? o4.y : expm1f(o4.y);
        o4.z = o4.z > 0.f ? o4.z : expm1f(o4.z);
        o4.w = o4.w > 0.f ? o4.w : expm1f(o4.w);
        ushort4 hv;
        hv.x = f2bf(o4.x); hv.y = f2bf(o4.y); hv.z = f2bf(o4.z); hv.w = f2bf(o4.w);
        *(ushort4*)(hb + (size_t)node * HD + lane * 4) = hv;
    } else {
        o4.x += __shfl_xor(o4.x, 16); o4.x += __shfl_xor(o4.x, 32);
        o4.y += __shfl_xor(o4.y, 16); o4.y += __shfl_xor(o4.y, 32);
        o4.z += __shfl_xor(o4.z, 16); o4.z += __shfl_xor(o4.z, 32);
        o4.w += __shfl_xor(o4.w, 16); o4.w += __shfl_xor(o4.w, 32);
        if (lane < 16) {
            float* po = out + (size_t)node * DH;
            po[0 * 16 + lane] = o4.x * 0.25f;
            po[1 * 16 + lane] = o4.y * 0.25f;
            po[2 * 16 + lane] = o4.z * 0.25f;
            po[3 * 16 + lane] = o4.w * 0.25f;
        }
    }
}

extern "C" void kernel_launch(void* const* d_in, const int* in_sizes, int n_in,
                              void* d_out, int out_size, void* d_ws, size_t ws_size,
                              hipStream_t stream) {
    const float* x   = (const float*)d_in[0];
    const int*   src = (const int*)d_in[1];
    const int*   dst = (const int*)d_in[2];
    const float* W[3]  = {(const float*)d_in[3], (const float*)d_in[7],  (const float*)d_in[11]};
    const float* al[3] = {(const float*)d_in[4], (const float*)d_in[8],  (const float*)d_in[12]};
    const float* ar[3] = {(const float*)d_in[5], (const float*)d_in[9],  (const float*)d_in[13]};
    const float* bb[3] = {(const float*)d_in[6], (const float*)d_in[10], (const float*)d_in[14]};

    size_t big = (size_t)N_NODES * HD;      // 12.8M elems
    unsigned short* featb = (unsigned short*)d_ws;
    unsigned short* hb1 = featb + big;
    unsigned short* hb2 = hb1 + big;
    float* el = (float*)(hb2 + big);
    float* er = el + (size_t)N_NODES * NHEAD;
    int* deg     = (int*)(er + (size_t)N_NODES * NHEAD);
    int* rowptr  = deg + 50048;
    int* cursor  = rowptr + 50048;
    int* csr_src = cursor + 50048;          // E ints
    int* bsum    = csr_src + N_EDGES;       // 64 ints
    unsigned short* Wp = (unsigned short*)(bsum + 64);  // 3*128*64*8

    const int NB = (N_NODES + 1023) / 1024;  // 49

    // ---- weight pack (+deg zero) + CSR build (once per launch) ----
    packw_k<<<384, 64, 0, stream>>>(W[0], W[1], W[2], Wp, deg);
    hist_k<<<(N_EDGES / 2 + 255) / 256, 256, 0, stream>>>(dst, deg);
    scan1_k<<<NB, 1024, 0, stream>>>(deg, rowptr, bsum);
    scan3_k<<<NB, 1024, 0, stream>>>(rowptr, bsum, cursor, NB);
    scatter_k<<<(N_EDGES / 2 + 255) / 256, 256, 0, stream>>>(src, dst, cursor, csr_src);

    int g0grid = (N_NODES + 63) / 64;       // 782
    int g2grid = (N_NODES + 127) / 128;     // 391
    int agrid = (N_NODES + 3) / 4;

    gemm0_k<<<g0grid, 256, 0, stream>>>(x, Wp, al[0], ar[0], featb, el, er, N_NODES);
    agg_k<0><<<agrid, 256, 0, stream>>>(rowptr, csr_src, el, er, featb,
                                        nullptr, bb[0], nullptr, hb1);
    gemm2_k<<<g2grid, 256, 0, stream>>>(hb1, Wp + (size_t)1 * 128 * 64 * 8,
                                        al[1], ar[1], featb, el, er, N_NODES);
    agg_k<1><<<agrid, 256, 0, stream>>>(rowptr, csr_src, el, er, featb,
                                        hb1, bb[1], nullptr, hb2);
    gemm2_k<<<g2grid, 256, 0, stream>>>(hb2, Wp + (size_t)2 * 128 * 64 * 8,
                                        al[2], ar[2], featb, el, er, N_NODES);
    agg_k<2><<<agrid, 256, 0, stream>>>(rowptr, csr_src, el, er, featb,
                                        hb2, bb[2], (float*)d_out, nullptr);
}

// Round 11
// 327.056 us; speedup vs baseline: 1.0964x; 1.0396x over previous
//
#include <hip/hip_runtime.h>
#include <math.h>

#define N_NODES 50000
#define N_EDGES 800000
#define HD 256      // H*D
#define NHEAD 4
#define DH 64
#define NPAD 50048

typedef short bf16x8 __attribute__((ext_vector_type(8)));
typedef float f32x4 __attribute__((ext_vector_type(4)));

__device__ __forceinline__ unsigned short f2bf(float f) {  // RNE
    unsigned u = __float_as_uint(f);
    return (unsigned short)((u + 0x7fffu + ((u >> 16) & 1u)) >> 16);
}
__device__ __forceinline__ float bf2f(unsigned short h) {
    return __uint_as_float((unsigned)h << 16);
}
// π: stored col c' holds original col orig(c') = (c'&~63) | ((c'&3)*16 + ((c'>>2)&15))
__device__ __forceinline__ int origk(int k) {
    return (k & ~63) | ((k & 3) * 16 + ((k >> 2) & 15));
}

// ---------- pack W into per-lane MFMA B-frag layout; also zero deg (4 copies) ----------
__global__ void packw_k(const float* __restrict__ W0, const float* __restrict__ W1,
                        const float* __restrict__ W2, unsigned short* __restrict__ Wp,
                        int* __restrict__ deg) {
    int blk = blockIdx.x;           // 384 = 3 layers * 128 tiles
    int L = blk >> 7, t = blk & 127;
    const float* W = L == 0 ? W0 : L == 1 ? W1 : W2;
    int nt = t >> 3, kt = t & 7;
    int lane = threadIdx.x;
    for (int i = blk * 64 + lane; i < 4 * NPAD; i += 384 * 64) deg[i] = 0;
    int col = nt * 16 + (lane & 15);
    int kb = kt * 32 + (lane >> 4) * 8;
    unsigned short v[8];
#pragma unroll
    for (int j = 0; j < 8; j++) {
        int k = kb + j;
        if (L > 0) k = origk(k);
        v[j] = f2bf(W[(size_t)k * 256 + col]);
    }
    *(bf16x8*)(Wp + ((size_t)(L * 128 + t) * 64 + lane) * 8) = *(bf16x8*)v;
}

// ---------- shared GEMM pieces ----------
__device__ __forceinline__ void mfma_tile(const unsigned short* Asl,
                                          const unsigned short* wbase,
                                          int lane, f32x4 acc[4][4]) {
#pragma unroll
    for (int kk = 0; kk < 8; kk++) {
        bf16x8 a[4], b[4];
#pragma unroll
        for (int m = 0; m < 4; m++) {
            int r = m * 16 + (lane & 15);
            int kb = kk * 32 + (lane >> 4) * 8;
            int byt = (r * 512 + kb * 2) ^ ((r & 7) << 4);
            a[m] = *(const bf16x8*)((const char*)Asl + byt);
        }
#pragma unroll
        for (int n = 0; n < 4; n++)
            b[n] = *(const bf16x8*)(wbase + ((size_t)(n * 8 + kk) * 64 + lane) * 8);
#pragma unroll
        for (int m = 0; m < 4; m++)
#pragma unroll
            for (int n = 0; n < 4; n++)
                acc[m][n] = __builtin_amdgcn_mfma_f32_16x16x32_bf16(a[m], b[n],
                                                                    acc[m][n], 0, 0, 0);
    }
}

// el/er butterfly + π-layout C store (el bf16, er fp32)
__device__ __forceinline__ void epilogue_tile(f32x4 acc[4][4], int bm, int wv, int lane,
                                              const float* __restrict__ al,
                                              const float* __restrict__ ar,
                                              unsigned short* __restrict__ C,
                                              unsigned short* __restrict__ el,
                                              float* __restrict__ er, int M) {
    int rr = lane >> 4, cc = lane & 15;
    float alv[4], arv[4];
#pragma unroll
    for (int n = 0; n < 4; n++) {
        alv[n] = al[wv * 64 + n * 16 + cc];
        arv[n] = ar[wv * 64 + n * 16 + cc];
    }
    float vl[16], vr[16];
#pragma unroll
    for (int m = 0; m < 4; m++)
#pragma unroll
        for (int r = 0; r < 4; r++) {
            float ep = 0.f, rp = 0.f;
#pragma unroll
            for (int n = 0; n < 4; n++) {
                ep = fmaf(acc[m][n][r], alv[n], ep);
                rp = fmaf(acc[m][n][r], arv[n], rp);
            }
            vl[m * 4 + r] = ep;
            vr[m * 4 + r] = rp;
        }
    float l8[8], r8[8];
#pragma unroll
    for (int i = 0; i < 8; i++) {
        float xs = (cc & 1) ? vl[2 * i] : vl[2 * i + 1];
        float xk = (cc & 1) ? vl[2 * i + 1] : vl[2 * i];
        l8[i] = xk + __shfl_xor(xs, 1);
        float ys = (cc & 1) ? vr[2 * i] : vr[2 * i + 1];
        float yk = (cc & 1) ? vr[2 * i + 1] : vr[2 * i];
        r8[i] = yk + __shfl_xor(ys, 1);
    }
    float l4[4], r4[4];
#pragma unroll
    for (int i = 0; i < 4; i++) {
        float xs = (cc & 2) ? l8[2 * i] : l8[2 * i + 1];
        float xk = (cc & 2) ? l8[2 * i + 1] : l8[2 * i];
        l4[i] = xk + __shfl_xor(xs, 2);
        float ys = (cc & 2) ? r8[2 * i] : r8[2 * i + 1];
        float yk = (cc & 2) ? r8[2 * i + 1] : r8[2 * i];
        r4[i] = yk + __shfl_xor(ys, 2);
    }
    float l2[2], r2[2];
#pragma unroll
    for (int i = 0; i < 2; i++) {
        float xs = (cc & 4) ? l4[2 * i] : l4[2 * i + 1];
        float xk = (cc & 4) ? l4[2 * i + 1] : l4[2 * i];
        l2[i] = xk + __shfl_xor(xs, 4);
        float ys = (cc & 4) ? r4[2 * i] : r4[2 * i + 1];
        float yk = (cc & 4) ? r4[2 * i + 1] : r4[2 * i];
        r2[i] = yk + __shfl_xor(ys, 4);
    }
    {
        float xs = (cc & 8) ? l2[0] : l2[1];
        float xk = (cc & 8) ? l2[1] : l2[0];
        float lv = xk + __shfl_xor(xs, 8);
        float ys = (cc & 8) ? r2[0] : r2[1];
        float yk = (cc & 8) ? r2[1] : r2[0];
        float rv = yk + __shfl_xor(ys, 8);
        int row_e = bm + (cc >> 2) * 16 + rr * 4 + (cc & 3);
        if (row_e < M) {
            el[(size_t)row_e * NHEAD + wv] = f2bf(lv);
            er[(size_t)row_e * NHEAD + wv] = rv;
        }
    }
#pragma unroll
    for (int m = 0; m < 4; m++) {
#pragma unroll
        for (int r = 0; r < 4; r++) {
            int row = bm + m * 16 + rr * 4 + r;
            if (row < M) {
                unsigned short p4[4] = {f2bf(acc[m][0][r]), f2bf(acc[m][1][r]),
                                        f2bf(acc[m][2][r]), f2bf(acc[m][3][r])};
                *(ushort4*)(C + (size_t)row * 256 + wv * 64 + cc * 4) = *(ushort4*)p4;
            }
        }
    }
}

// ---------- layer-0 GEMM: fp32 A, 1 tile/block ----------
__global__ __launch_bounds__(256) void gemm0_k(const float* __restrict__ A,
                                               const unsigned short* __restrict__ Wp,
                                               const float* __restrict__ al,
                                               const float* __restrict__ ar,
                                               unsigned short* __restrict__ C,
                                               unsigned short* __restrict__ el,
                                               float* __restrict__ er, int M) {
    __shared__ unsigned short Asl[64 * 256];
    int tid = threadIdx.x, wv = tid >> 6, lane = tid & 63;
    int bm = blockIdx.x * 64;
#pragma unroll
    for (int i = 0; i < 8; i++) {
        int chunk = i * 256 + tid;
        int r = chunk >> 5, kc = (chunk & 31) * 8;
        float4 f0, f1;
        if (bm + r < M) {
            const float* p = A + (size_t)(bm + r) * 256 + kc;
            f0 = *(const float4*)p;
            f1 = *(const float4*)(p + 4);
        } else {
            f0 = f1 = make_float4(0.f, 0.f, 0.f, 0.f);
        }
        unsigned short tmp[8] = {f2bf(f0.x), f2bf(f0.y), f2bf(f0.z), f2bf(f0.w),
                                 f2bf(f1.x), f2bf(f1.y), f2bf(f1.z), f2bf(f1.w)};
        int b = (r * 512 + kc * 2) ^ ((r & 7) << 4);
        *(bf16x8*)((char*)Asl + b) = *(bf16x8*)tmp;
    }
    __syncthreads();
    const unsigned short* wbase = Wp + (size_t)(wv * 4) * 8 * 64 * 8;
    f32x4 acc[4][4] = {};
    mfma_tile(Asl, wbase, lane, acc);
    epilogue_tile(acc, bm, wv, lane, al, ar, C, el, er, M);
}

// ---------- layers 1/2 GEMM: bf16 A, 2 tiles/block, async dbuf (counted vmcnt) ----------
__global__ __launch_bounds__(256) void gemm2_k(const unsigned short* __restrict__ A,
                                               const unsigned short* __restrict__ Wp,
                                               const float* __restrict__ al,
                                               const float* __restrict__ ar,
                                               unsigned short* __restrict__ C,
                                               unsigned short* __restrict__ el,
                                               float* __restrict__ er, int M) {
    __shared__ unsigned short Asl[2][64 * 256];   // 64 KB
    int tid = threadIdx.x, wv = tid >> 6, lane = tid & 63;
    int bm0 = blockIdx.x * 128, bm1 = bm0 + 64;
#pragma unroll
    for (int i = 0; i < 8; i++) {
        int chunk = i * 256 + tid;
        int r = chunk >> 5;
        int c16 = (chunk & 31) ^ (r & 7);
        int grow = bm0 + r; if (grow >= M) grow = M - 1;
        __builtin_amdgcn_global_load_lds(
            (const __attribute__((address_space(1))) unsigned int*)
                (A + (size_t)grow * 256 + c16 * 8),
            (__attribute__((address_space(3))) unsigned int*)
                ((char*)Asl[0] + (size_t)chunk * 16),
            16, 0, 0);
    }
#pragma unroll
    for (int i = 0; i < 8; i++) {
        int chunk = i * 256 + tid;
        int r = chunk >> 5;
        int c16 = (chunk & 31) ^ (r & 7);
        int grow = bm1 + r; if (grow >= M) grow = M - 1;
        __builtin_amdgcn_global_load_lds(
            (const __attribute__((address_space(1))) unsigned int*)
                (A + (size_t)grow * 256 + c16 * 8),
            (__attribute__((address_space(3))) unsigned int*)
                ((char*)Asl[1] + (size_t)chunk * 16),
            16, 0, 0);
    }
    asm volatile("s_waitcnt vmcnt(8)" ::: "memory");   // tile0 landed; tile1 in flight
    __builtin_amdgcn_sched_barrier(0);
    __builtin_amdgcn_s_barrier();
    const unsigned short* wbase = Wp + (size_t)(wv * 4) * 8 * 64 * 8;
    f32x4 acc[4][4] = {};
    mfma_tile(Asl[0], wbase, lane, acc);
    asm volatile("s_waitcnt vmcnt(0)" ::: "memory");
    __builtin_amdgcn_sched_barrier(0);
    __builtin_amdgcn_s_barrier();
    epilogue_tile(acc, bm0, wv, lane, al, ar, C, el, er, M);
    f32x4 acc2[4][4] = {};
    mfma_tile(Asl[1], wbase, lane, acc2);
    epilogue_tile(acc2, bm1, wv, lane, al, ar, C, el, er, M);
}

// ---------- CSR build ----------
// 4-way split histogram: thread t adds into copy t&3 → same-address contention /4
__global__ void hist_k(const int* __restrict__ dst, int* __restrict__ deg) {
    int t = blockIdx.x * 256 + threadIdx.x;
    int e = t * 2;
    int* mydeg = deg + (size_t)(threadIdx.x & 3) * NPAD;
    if (e + 1 < N_EDGES) {
        int2 d2 = *(const int2*)(dst + e);
        atomicAdd(&mydeg[d2.x], 1);
        atomicAdd(&mydeg[d2.y], 1);
    } else if (e < N_EDGES) {
        atomicAdd(&mydeg[dst[e]], 1);
    }
}

__global__ __launch_bounds__(1024) void scan1_k(const int* __restrict__ deg,
                                                int* __restrict__ rowptr,
                                                int* __restrict__ bsum) {
    __shared__ int wsum[16];
    int tid = threadIdx.x, lane = tid & 63, wv = tid >> 6;
    int i = blockIdx.x * 1024 + tid;
    int v = 0;
    if (i < N_NODES)
        v = deg[i] + deg[i + NPAD] + deg[i + 2 * NPAD] + deg[i + 3 * NPAD];
    int sc = v;
#pragma unroll
    for (int o = 1; o < 64; o <<= 1) {
        int t = __shfl_up(sc, o);
        if (lane >= o) sc += t;
    }
    if (lane == 63) wsum[wv] = sc;
    __syncthreads();
    if (wv == 0 && lane < 16) {
        int ws = wsum[lane];
#pragma unroll
        for (int o = 1; o < 16; o <<= 1) {
            int t = __shfl_up(ws, o);
            if (lane >= o) ws += t;
        }
        wsum[lane] = ws;
    }
    __syncthreads();
    int incl = sc + (wv > 0 ? wsum[wv - 1] : 0);
    if (i < N_NODES) rowptr[i + 1] = incl;
    if (tid == 1023) bsum[blockIdx.x] = incl;
}

__global__ __launch_bounds__(1024) void scan3_k(int* __restrict__ rowptr,
                                                const int* __restrict__ bsum,
                                                int* __restrict__ cursor, int nb) {
    __shared__ int boff_s;
    int tid = threadIdx.x;
    if (tid < 64) {
        int v = (tid < nb) ? bsum[tid] : 0;
        int sc = v;
#pragma unroll
        for (int o = 1; o < 64; o <<= 1) {
            int t = __shfl_up(sc, o);
            if ((tid & 63) >= o) sc += t;
        }
        if (tid == (int)blockIdx.x) boff_s = sc - v;  // exclusive prefix
    }
    __syncthreads();
    int off = boff_s;
    int i = blockIdx.x * 1024 + tid;
    if (blockIdx.x == 0 && tid == 0) { rowptr[0] = 0; cursor[0] = 0; }
    if (i < N_NODES) {
        int v = rowptr[i + 1] + off;
        rowptr[i + 1] = v;
        if (i + 1 < N_NODES) cursor[i + 1] = v;
    }
}

__global__ void scatter_k(const int* __restrict__ src, const int* __restrict__ dst,
                          int* __restrict__ cursor, int* __restrict__ csr_src) {
    int e = (blockIdx.x * 256 + threadIdx.x) * 2;
    if (e + 1 < N_EDGES) {
        int2 s2 = *(const int2*)(src + e);
        int2 d2 = *(const int2*)(dst + e);
        csr_src[atomicAdd(&cursor[d2.x], 1)] = s2.x;
        csr_src[atomicAdd(&cursor[d2.y], 1)] = s2.y;
    } else if (e < N_EDGES) {
        csr_src[atomicAdd(&cursor[dst[e]], 1)] = src[e];
    }
}

// ---------- fused per-dst softmax (max-free) + gather-aggregate + epilogue ----------
// feat/resid/hb in π layout. el bf16. MODE 0: no resid, ELU; MODE 1: resid, ELU;
// MODE 2: resid, no act, head-mean, fp32 out (unpermuted)
template <int MODE>
__global__ __launch_bounds__(256) void agg_k(const int* __restrict__ rowptr,
                                             const int* __restrict__ csr_src,
                                             const unsigned short* __restrict__ el,
                                             const float* __restrict__ er,
                                             const unsigned short* __restrict__ feat,
                                             const unsigned short* __restrict__ resid,
                                             const float* __restrict__ bias,
                                             float* __restrict__ out,
                                             unsigned short* __restrict__ hb) {
    __shared__ int   ws_s[4][64];       // byte offsets s*512
    __shared__ float ws_w[4][4][68];    // [wave][head][edge], pad 68 de-banks
    int wv = threadIdx.x >> 6, lane = threadIdx.x & 63;
    int node = blockIdx.x * 4 + wv;
    if (node >= N_NODES) return;
    int beg = rowptr[node], end = rowptr[node + 1];
    float4 er4 = *(const float4*)(er + (size_t)node * 4);
    float4 acc0 = make_float4(0.f, 0.f, 0.f, 0.f);
    float4 acc1 = make_float4(0.f, 0.f, 0.f, 0.f);
    float4 den = make_float4(0.f, 0.f, 0.f, 0.f);
    int h = lane >> 4;
    int l8 = lane * 8;
    const char* fb = (const char*)feat;
    for (int base = beg; base < end; base += 64) {
        int j = base + lane;
        int soff = 0;
        float4 w = make_float4(0.f, 0.f, 0.f, 0.f);
        if (j < end) {
            int s = csr_src[j];
            soff = s << 9;              // byte offset of feat row (256 bf16)
            ushort4 l4u = *(const ushort4*)(el + (size_t)s * 4);
            float vx = bf2f(l4u.x) + er4.x; vx = vx > 0.f ? vx : 0.2f * vx;
            float vy = bf2f(l4u.y) + er4.y; vy = vy > 0.f ? vy : 0.2f * vy;
            float vz = bf2f(l4u.z) + er4.z; vz = vz > 0.f ? vz : 0.2f * vz;
            float vw = bf2f(l4u.w) + er4.w; vw = vw > 0.f ? vw : 0.2f * vw;
            // max-free softmax: |v| = O(3), exp cannot overflow fp32
            w.x = expf(vx); w.y = expf(vy); w.z = expf(vz); w.w = expf(vw);
            den.x += w.x; den.y += w.y; den.z += w.z; den.w += w.w;
        }
        ws_s[wv][lane] = soff;          // dummy lanes: soff=0, w=0
        ws_w[wv][0][lane] = w.x;
        ws_w[wv][1][lane] = w.y;
        ws_w[wv][2][lane] = w.z;
        ws_w[wv][3][lane] = w.w;
        __builtin_amdgcn_wave_barrier();
        int cnt = end - base; if (cnt > 64) cnt = 64;
        int cnt4 = (cnt + 3) & ~3;      // zero-padded: no tail loop
        for (int k = 0; k < cnt4; k += 4) {
            int4   so = *(const int4*)&ws_s[wv][k];      // broadcast
            float4 w4 = *(const float4*)&ws_w[wv][h][k];
            ushort4 u0 = *(const ushort4*)(fb + (so.x + l8));
            ushort4 u1 = *(const ushort4*)(fb + (so.y + l8));
            ushort4 u2 = *(const ushort4*)(fb + (so.z + l8));
            ushort4 u3 = *(const ushort4*)(fb + (so.w + l8));
            acc0.x = fmaf(w4.x, bf2f(u0.x), acc0.x);
            acc0.y = fmaf(w4.x, bf2f(u0.y), acc0.y);
            acc0.z = fmaf(w4.x, bf2f(u0.z), acc0.z);
            acc0.w = fmaf(w4.x, bf2f(u0.w), acc0.w);
            acc1.x = fmaf(w4.y, bf2f(u1.x), acc1.x);
            acc1.y = fmaf(w4.y, bf2f(u1.y), acc1.y);
            acc1.z = fmaf(w4.y, bf2f(u1.z), acc1.z);
            acc1.w = fmaf(w4.y, bf2f(u1.w), acc1.w);
            acc0.x = fmaf(w4.z, bf2f(u2.x), acc0.x);
            acc0.y = fmaf(w4.z, bf2f(u2.y), acc0.y);
            acc0.z = fmaf(w4.z, bf2f(u2.z), acc0.z);
            acc0.w = fmaf(w4.z, bf2f(u2.w), acc0.w);
            acc1.x = fmaf(w4.w, bf2f(u3.x), acc1.x);
            acc1.y = fmaf(w4.w, bf2f(u3.y), acc1.y);
            acc1.z = fmaf(w4.w, bf2f(u3.z), acc1.z);
            acc1.w = fmaf(w4.w, bf2f(u3.w), acc1.w);
        }
        __builtin_amdgcn_wave_barrier();
    }
    float4 acc;
    acc.x = acc0.x + acc1.x; acc.y = acc0.y + acc1.y;
    acc.z = acc0.z + acc1.z; acc.w = acc0.w + acc1.w;
#pragma unroll
    for (int o = 1; o < 64; o <<= 1) {
        den.x += __shfl_xor(den.x, o);
        den.y += __shfl_xor(den.y, o);
        den.z += __shfl_xor(den.z, o);
        den.w += __shfl_xor(den.w, o);
    }
    float den_me = h == 0 ? den.x : h == 1 ? den.y : h == 2 ? den.z : den.w;
    float r = den_me > 0.f ? 1.f / den_me : 0.f;
    int cc = lane & 15;
    float4 b4;
    b4.x = bias[h * 64 + 0 * 16 + cc];
    b4.y = bias[h * 64 + 1 * 16 + cc];
    b4.z = bias[h * 64 + 2 * 16 + cc];
    b4.w = bias[h * 64 + 3 * 16 + cc];
    float4 o4;
    o4.x = acc.x * r + b4.x;
    o4.y = acc.y * r + b4.y;
    o4.z = acc.z * r + b4.z;
    o4.w = acc.w * r + b4.w;
    if (MODE >= 1) {
        ushort4 r4 = *(const ushort4*)(resid + (size_t)node * HD + lane * 4);
        o4.x += bf2f(r4.x); o4.y += bf2f(r4.y);
        o4.z += bf2f(r4.z); o4.w += bf2f(r4.w);
    }
    if (MODE <= 1) {
        o4.x = o4.x > 0.f ? o4.x : expm1f(o4.x);
        o4.y = o4.y > 0.f ? o4.y : expm1f(o4.y);
        o4.z = o4.z > 0.f ? o4.z : expm1f(o4.z);
        o4.w = o4.w > 0.f ? o4.w : expm1f(o4.w);
        ushort4 hv;
        hv.x = f2bf(o4.x); hv.y = f2bf(o4.y); hv.z = f2bf(o4.z); hv.w = f2bf(o4.w);
        *(ushort4*)(hb + (size_t)node * HD + lane * 4) = hv;
    } else {
        o4.x += __shfl_xor(o4.x, 16); o4.x += __shfl_xor(o4.x, 32);
        o4.y += __shfl_xor(o4.y, 16); o4.y += __shfl_xor(o4.y, 32);
        o4.z += __shfl_xor(o4.z, 16); o4.z += __shfl_xor(o4.z, 32);
        o4.w += __shfl_xor(o4.w, 16); o4.w += __shfl_xor(o4.w, 32);
        if (lane < 16) {
            float* po = out + (size_t)node * DH;
            po[0 * 16 + lane] = o4.x * 0.25f;
            po[1 * 16 + lane] = o4.y * 0.25f;
            po[2 * 16 + lane] = o4.z * 0.25f;
            po[3 * 16 + lane] = o4.w * 0.25f;
        }
    }
}

extern "C" void kernel_launch(void* const* d_in, const int* in_sizes, int n_in,
                              void* d_out, int out_size, void* d_ws, size_t ws_size,
                              hipStream_t stream) {
    const float* x   = (const float*)d_in[0];
    const int*   src = (const int*)d_in[1];
    const int*   dst = (const int*)d_in[2];
    const float* W[3]  = {(const float*)d_in[3], (const float*)d_in[7],  (const float*)d_in[11]};
    const float* al[3] = {(const float*)d_in[4], (const float*)d_in[8],  (const float*)d_in[12]};
    const float* ar[3] = {(const float*)d_in[5], (const float*)d_in[9],  (const float*)d_in[13]};
    const float* bb[3] = {(const float*)d_in[6], (const float*)d_in[10], (const float*)d_in[14]};

    size_t big = (size_t)N_NODES * HD;      // 12.8M elems
    unsigned short* featb = (unsigned short*)d_ws;
    unsigned short* hb1 = featb + big;
    unsigned short* hb2 = hb1 + big;
    unsigned short* el = hb2 + big;          // bf16, N*4
    float* er = (float*)(el + (size_t)NPAD * NHEAD);
    int* deg     = (int*)(er + (size_t)NPAD * NHEAD);   // 4 copies
    int* rowptr  = deg + 4 * NPAD;
    int* cursor  = rowptr + NPAD;
    int* csr_src = cursor + NPAD;           // E ints
    int* bsum    = csr_src + N_EDGES;       // 64 ints
    unsigned short* Wp = (unsigned short*)(bsum + 64);  // 3*128*64*8

    const int NB = (N_NODES + 1023) / 1024;  // 49

    // ---- weight pack (+deg zero) + CSR build (once per launch) ----
    packw_k<<<384, 64, 0, stream>>>(W[0], W[1], W[2], Wp, deg);
    hist_k<<<(N_EDGES / 2 + 255) / 256, 256, 0, stream>>>(dst, deg);
    scan1_k<<<NB, 1024, 0, stream>>>(deg, rowptr, bsum);
    scan3_k<<<NB, 1024, 0, stream>>>(rowptr, bsum, cursor, NB);
    scatter_k<<<(N_EDGES / 2 + 255) / 256, 256, 0, stream>>>(src, dst, cursor, csr_src);

    int g0grid = (N_NODES + 63) / 64;       // 782
    int g2grid = (N_NODES + 127) / 128;     // 391
    int agrid = (N_NODES + 3) / 4;

    gemm0_k<<<g0grid, 256, 0, stream>>>(x, Wp, al[0], ar[0], featb, el, er, N_NODES);
    agg_k<0><<<agrid, 256, 0, stream>>>(rowptr, csr_src, el, er, featb,
                                        nullptr, bb[0], nullptr, hb1);
    gemm2_k<<<g2grid, 256, 0, stream>>>(hb1, Wp + (size_t)1 * 128 * 64 * 8,
                                        al[1], ar[1], featb, el, er, N_NODES);
    agg_k<1><<<agrid, 256, 0, stream>>>(rowptr, csr_src, el, er, featb,
                                        hb1, bb[1], nullptr, hb2);
    gemm2_k<<<g2grid, 256, 0, stream>>>(hb2, Wp + (size_t)2 * 128 * 64 * 8,
                                        al[2], ar[2], featb, el, er, N_NODES);
    agg_k<2><<<agrid, 256, 0, stream>>>(rowptr, csr_src, el, er, featb,
                                        hb2, bb[2], (float*)d_out, nullptr);
}